// Round 1
// baseline (2502.446 us; speedup 1.0000x reference)
//
#include <hip/hip_runtime.h>
#include <hip/hip_bf16.h>
#include <cstdint>
#include <cmath>

#define T_SEQ 2048
#define C_DIM 3072
#define NH    24
#define NKV   8
#define HD    128

// ---------------------------------------------------------------------------
// ws layout (floats):
//   cosT [2048][64]            131072
//   sinT [2048][64]            131072
//   Qh   [24][2048][128]       6291456
//   Kh   [ 8][2048][128]       2097152
//   Vh   [ 8][2048][128]       2097152
//   AO   [2048][3072]          6291456
// total = 17039360 floats = 68.2 MB
// ---------------------------------------------------------------------------

__global__ __launch_bounds__(64) void rope_table(float* __restrict__ cosT,
                                                 float* __restrict__ sinT) {
    int t = blockIdx.x;        // 0..2047
    int j = threadIdx.x;       // 0..63
    // inv_freq[j] = 10000^(-j/64)
    float inv = powf(10000.0f, -(float)j * (1.0f / 64.0f));
    float ang = (float)t * inv;
    cosT[t * 64 + j] = cosf(ang);
    sinT[t * 64 + j] = sinf(ang);
}

// ---------------------------------------------------------------------------
// Fused QKV projection GEMM.
// A = x [2048, 3072] row-major. Column tiles of 128:
//   bx 0..23  -> Wq head bx   -> Qh[bx][t][d]
//   bx 24..31 -> Wk head bx-24-> Kh[..][t][d]
//   bx 32..39 -> Wv head bx-32-> Vh[..][t][d]
// 256 threads, BM=BN=128, BK=16, 8x8 micro-tile per thread.
// Thread cols = {tx*4..tx*4+3} U {64+tx*4..67+tx*4} (bank-friendly b128 reads)
// ---------------------------------------------------------------------------
__global__ __launch_bounds__(256) void qkv_gemm(
    const float* __restrict__ x,
    const float* __restrict__ Wq, const float* __restrict__ Wk,
    const float* __restrict__ Wv,
    float* __restrict__ Qh, float* __restrict__ Kh, float* __restrict__ Vh) {

    __shared__ float sA[16][132];   // transposed: sA[k][m]
    __shared__ float sB[16][132];   // sB[k][n]

    const int bx = blockIdx.x;      // 0..39 column tile (== one head)
    const int by = blockIdx.y;      // 0..15 row tile
    const int tid = threadIdx.x;
    const int tx = tid & 15;        // 0..15
    const int ty = tid >> 4;        // 0..15

    const float* B;
    int ldb;
    float* dst;
    if (bx < 24)      { B = Wq + bx * 128;        ldb = 3072; dst = Qh + (size_t)bx * T_SEQ * HD; }
    else if (bx < 32) { B = Wk + (bx - 24) * 128; ldb = 1024; dst = Kh + (size_t)(bx - 24) * T_SEQ * HD; }
    else              { B = Wv + (bx - 32) * 128; ldb = 1024; dst = Vh + (size_t)(bx - 32) * T_SEQ * HD; }

    const int m0 = by * 128;
    const float* A = x + (size_t)m0 * C_DIM;

    float acc[8][8];
    #pragma unroll
    for (int i = 0; i < 8; ++i)
        #pragma unroll
        for (int j = 0; j < 8; ++j) acc[i][j] = 0.0f;

    for (int k0 = 0; k0 < C_DIM; k0 += 16) {
        __syncthreads();
        // stage A tile 128x16 (transposed into sA[k][m])
        #pragma unroll
        for (int u = 0; u < 2; ++u) {
            int f  = tid * 2 + u;          // 0..511
            int r  = f >> 2;               // 0..127
            int c4 = (f & 3) * 4;          // 0,4,8,12
            float4 v = *reinterpret_cast<const float4*>(A + (size_t)r * C_DIM + k0 + c4);
            sA[c4 + 0][r] = v.x; sA[c4 + 1][r] = v.y;
            sA[c4 + 2][r] = v.z; sA[c4 + 3][r] = v.w;
        }
        // stage B tile 16x128
        #pragma unroll
        for (int u = 0; u < 2; ++u) {
            int f  = tid * 2 + u;
            int kk = f >> 5;               // 0..15
            int c4 = (f & 31) * 4;         // 0..124
            float4 v = *reinterpret_cast<const float4*>(B + (size_t)(k0 + kk) * ldb + c4);
            *reinterpret_cast<float4*>(&sB[kk][c4]) = v;
        }
        __syncthreads();

        #pragma unroll
        for (int kk = 0; kk < 16; ++kk) {
            float4 a0 = *reinterpret_cast<const float4*>(&sA[kk][ty * 8]);
            float4 a1 = *reinterpret_cast<const float4*>(&sA[kk][ty * 8 + 4]);
            float4 b0 = *reinterpret_cast<const float4*>(&sB[kk][tx * 4]);
            float4 b1 = *reinterpret_cast<const float4*>(&sB[kk][tx * 4 + 64]);
            float a[8] = {a0.x, a0.y, a0.z, a0.w, a1.x, a1.y, a1.z, a1.w};
            float b[8] = {b0.x, b0.y, b0.z, b0.w, b1.x, b1.y, b1.z, b1.w};
            #pragma unroll
            for (int i = 0; i < 8; ++i)
                #pragma unroll
                for (int j = 0; j < 8; ++j)
                    acc[i][j] = fmaf(a[i], b[j], acc[i][j]);
        }
    }

    // epilogue: dst[t][d], d in {tx*4..+3} and {64+tx*4..+3}
    #pragma unroll
    for (int i = 0; i < 8; ++i) {
        int t = m0 + ty * 8 + i;
        float4 v0 = make_float4(acc[i][0], acc[i][1], acc[i][2], acc[i][3]);
        float4 v1 = make_float4(acc[i][4], acc[i][5], acc[i][6], acc[i][7]);
        *reinterpret_cast<float4*>(dst + (size_t)t * HD + tx * 4)      = v0;
        *reinterpret_cast<float4*>(dst + (size_t)t * HD + 64 + tx * 4) = v1;
    }
}

// ---------------------------------------------------------------------------
// In-place RoPE on Qh (24 heads) and Kh (8 heads).
// grid (2048, 8), 256 threads: sub-head = tid>>6 (4 per block), j = tid&63.
// ---------------------------------------------------------------------------
__global__ __launch_bounds__(256) void rope_apply(
    float* __restrict__ Qh, float* __restrict__ Kh,
    const float* __restrict__ cosT, const float* __restrict__ sinT) {
    int t   = blockIdx.x;
    int sub = threadIdx.x >> 6;
    int j   = threadIdx.x & 63;
    int hh  = blockIdx.y * 4 + sub;   // 0..31: 0..23 = Q heads, 24..31 = K heads
    float* p = (hh < 24) ? (Qh + ((size_t)hh * T_SEQ + t) * HD)
                         : (Kh + ((size_t)(hh - 24) * T_SEQ + t) * HD);
    float c  = cosT[t * 64 + j];
    float s  = sinT[t * 64 + j];
    float x1 = p[j];
    float x2 = p[j + 64];
    p[j]      = fmaf(x1, c, -(x2 * s));
    p[j + 64] = fmaf(x2, c,  (x1 * s));
}

// ---------------------------------------------------------------------------
// Flash-style causal attention, fp32, GQA (h -> kv head h/3).
// grid (32 q-tiles, 24 heads), 256 threads.
// Q tile 64x128 in LDS; loop over 64-key tiles (kt <= qt).
// S-phase: thread (qb=tid>>4, kb=tid&15) computes 4x4 scores at rows qb+16i,
//          cols kb+16j, float4 over d.
// softmax: 4 threads per row, shuffle-reduced, online m/l state in LDS.
// O-phase: thread owns rows rb+16i (rb=tid>>4), dims db..db+7 (db=(tid&15)*8).
// ---------------------------------------------------------------------------
__global__ __launch_bounds__(256) void attn_kernel(
    const float* __restrict__ Qh, const float* __restrict__ Kh,
    const float* __restrict__ Vh, float* __restrict__ AO) {

    __shared__ float sQ[64][132];
    __shared__ float sK[64][132];
    __shared__ float sV[64][132];
    __shared__ float sS[64][68];
    __shared__ float sM[64], sL[64], sAl[64];

    const int qt  = blockIdx.x;   // 0..31
    const int h   = blockIdx.y;   // 0..23
    const int kh  = h / 3;
    const int tid = threadIdx.x;

    const float* Qp = Qh + ((size_t)h * T_SEQ + qt * 64) * HD;
    const float* Kp = Kh + (size_t)kh * T_SEQ * HD;
    const float* Vp = Vh + (size_t)kh * T_SEQ * HD;

    // load Q tile: 64x128 floats = 2048 float4, 8 per thread
    #pragma unroll
    for (int u = 0; u < 8; ++u) {
        int f  = tid + 256 * u;
        int r  = f >> 5;
        int c4 = (f & 31) * 4;
        *reinterpret_cast<float4*>(&sQ[r][c4]) =
            *reinterpret_cast<const float4*>(Qp + (size_t)r * HD + c4);
    }
    if (tid < 64) { sM[tid] = -INFINITY; sL[tid] = 0.0f; }

    const int qb = tid >> 4;          // 0..15
    const int kb = tid & 15;          // 0..15
    const int rb = tid >> 4;          // 0..15
    const int db = (tid & 15) * 8;    // 0..120

    float o[4][8];
    #pragma unroll
    for (int i = 0; i < 4; ++i)
        #pragma unroll
        for (int j = 0; j < 8; ++j) o[i][j] = 0.0f;

    const float scale = 0.08838834764831845f;  // 1/sqrt(128)

    for (int kt = 0; kt <= qt; ++kt) {
        __syncthreads();   // prev O-phase done before overwriting K/V (and Q load on iter 0)
        #pragma unroll
        for (int u = 0; u < 8; ++u) {
            int f  = tid + 256 * u;
            int r  = f >> 5;
            int c4 = (f & 31) * 4;
            *reinterpret_cast<float4*>(&sK[r][c4]) =
                *reinterpret_cast<const float4*>(Kp + ((size_t)(kt * 64 + r)) * HD + c4);
            *reinterpret_cast<float4*>(&sV[r][c4]) =
                *reinterpret_cast<const float4*>(Vp + ((size_t)(kt * 64 + r)) * HD + c4);
        }
        __syncthreads();

        // ---- S phase ----
        float s_acc[4][4];
        #pragma unroll
        for (int i = 0; i < 4; ++i)
            #pragma unroll
            for (int j = 0; j < 4; ++j) s_acc[i][j] = 0.0f;

        #pragma unroll 4
        for (int d = 0; d < 128; d += 4) {
            float4 a[4], b[4];
            #pragma unroll
            for (int i = 0; i < 4; ++i)
                a[i] = *reinterpret_cast<const float4*>(&sQ[qb + 16 * i][d]);
            #pragma unroll
            for (int j = 0; j < 4; ++j)
                b[j] = *reinterpret_cast<const float4*>(&sK[kb + 16 * j][d]);
            #pragma unroll
            for (int i = 0; i < 4; ++i)
                #pragma unroll
                for (int j = 0; j < 4; ++j) {
                    s_acc[i][j] = fmaf(a[i].x, b[j].x, s_acc[i][j]);
                    s_acc[i][j] = fmaf(a[i].y, b[j].y, s_acc[i][j]);
                    s_acc[i][j] = fmaf(a[i].z, b[j].z, s_acc[i][j]);
                    s_acc[i][j] = fmaf(a[i].w, b[j].w, s_acc[i][j]);
                }
        }

        const bool diag = (kt == qt);
        #pragma unroll
        for (int i = 0; i < 4; ++i) {
            int q = qb + 16 * i;
            #pragma unroll
            for (int j = 0; j < 4; ++j) {
                int k = kb + 16 * j;
                float sv = s_acc[i][j] * scale;
                if (diag && k > q) sv = -3.0e38f;   // causal mask
                sS[q][k] = sv;
            }
        }
        __syncthreads();

        // ---- online softmax ----
        {
            int r  = tid >> 2;
            int sl = tid & 3;
            float vals[16];
            float mpart = -3.0e38f;
            #pragma unroll
            for (int j = 0; j < 16; ++j) {
                vals[j] = sS[r][sl * 16 + j];
                mpart = fmaxf(mpart, vals[j]);
            }
            mpart = fmaxf(mpart, __shfl_xor(mpart, 1));
            mpart = fmaxf(mpart, __shfl_xor(mpart, 2));
            float mold = sM[r];
            float mnew = fmaxf(mold, mpart);
            float psum = 0.0f;
            #pragma unroll
            for (int j = 0; j < 16; ++j) {
                float p = __expf(vals[j] - mnew);
                sS[r][sl * 16 + j] = p;
                psum += p;
            }
            psum += __shfl_xor(psum, 1);
            psum += __shfl_xor(psum, 2);
            if (sl == 0) {
                float alpha = __expf(mold - mnew);
                sAl[r] = alpha;
                sL[r]  = sL[r] * alpha + psum;
                sM[r]  = mnew;
            }
        }
        __syncthreads();

        // ---- O phase ----
        float al[4];
        #pragma unroll
        for (int i = 0; i < 4; ++i) al[i] = sAl[rb + 16 * i];
        #pragma unroll
        for (int i = 0; i < 4; ++i)
            #pragma unroll
            for (int j = 0; j < 8; ++j) o[i][j] *= al[i];

        #pragma unroll 4
        for (int k = 0; k < 64; ++k) {
            float4 v0 = *reinterpret_cast<const float4*>(&sV[k][db]);
            float4 v1 = *reinterpret_cast<const float4*>(&sV[k][db + 4]);
            #pragma unroll
            for (int i = 0; i < 4; ++i) {
                float p = sS[rb + 16 * i][k];
                o[i][0] = fmaf(p, v0.x, o[i][0]);
                o[i][1] = fmaf(p, v0.y, o[i][1]);
                o[i][2] = fmaf(p, v0.z, o[i][2]);
                o[i][3] = fmaf(p, v0.w, o[i][3]);
                o[i][4] = fmaf(p, v1.x, o[i][4]);
                o[i][5] = fmaf(p, v1.y, o[i][5]);
                o[i][6] = fmaf(p, v1.z, o[i][6]);
                o[i][7] = fmaf(p, v1.w, o[i][7]);
            }
        }
    }

    // epilogue: divide by l, write AO[t][h*128 + d]
    #pragma unroll
    for (int i = 0; i < 4; ++i) {
        int r = rb + 16 * i;
        float inv = 1.0f / sL[r];
        int t = qt * 64 + r;
        float4 w0 = make_float4(o[i][0] * inv, o[i][1] * inv, o[i][2] * inv, o[i][3] * inv);
        float4 w1 = make_float4(o[i][4] * inv, o[i][5] * inv, o[i][6] * inv, o[i][7] * inv);
        *reinterpret_cast<float4*>(AO + (size_t)t * C_DIM + h * HD + db)     = w0;
        *reinterpret_cast<float4*>(AO + (size_t)t * C_DIM + h * HD + db + 4) = w1;
    }
}

// ---------------------------------------------------------------------------
// Output projection GEMM: AO [2048,3072] @ Wo [3072,3072] -> out [2048,3072]
// ---------------------------------------------------------------------------
__global__ __launch_bounds__(256) void out_gemm(
    const float* __restrict__ A_, const float* __restrict__ Bw,
    float* __restrict__ Cmat) {

    __shared__ float sA[16][132];
    __shared__ float sB[16][132];

    const int bx = blockIdx.x;   // 0..23
    const int by = blockIdx.y;   // 0..15
    const int tid = threadIdx.x;
    const int tx = tid & 15;
    const int ty = tid >> 4;

    const int n0 = bx * 128;
    const int m0 = by * 128;
    const float* A = A_ + (size_t)m0 * C_DIM;
    const float* B = Bw + n0;

    float acc[8][8];
    #pragma unroll
    for (int i = 0; i < 8; ++i)
        #pragma unroll
        for (int j = 0; j < 8; ++j) acc[i][j] = 0.0f;

    for (int k0 = 0; k0 < C_DIM; k0 += 16) {
        __syncthreads();
        #pragma unroll
        for (int u = 0; u < 2; ++u) {
            int f  = tid * 2 + u;
            int r  = f >> 2;
            int c4 = (f & 3) * 4;
            float4 v = *reinterpret_cast<const float4*>(A + (size_t)r * C_DIM + k0 + c4);
            sA[c4 + 0][r] = v.x; sA[c4 + 1][r] = v.y;
            sA[c4 + 2][r] = v.z; sA[c4 + 3][r] = v.w;
        }
        #pragma unroll
        for (int u = 0; u < 2; ++u) {
            int f  = tid * 2 + u;
            int kk = f >> 5;
            int c4 = (f & 31) * 4;
            float4 v = *reinterpret_cast<const float4*>(B + (size_t)(k0 + kk) * C_DIM + c4);
            *reinterpret_cast<float4*>(&sB[kk][c4]) = v;
        }
        __syncthreads();

        #pragma unroll
        for (int kk = 0; kk < 16; ++kk) {
            float4 a0 = *reinterpret_cast<const float4*>(&sA[kk][ty * 8]);
            float4 a1 = *reinterpret_cast<const float4*>(&sA[kk][ty * 8 + 4]);
            float4 b0 = *reinterpret_cast<const float4*>(&sB[kk][tx * 4]);
            float4 b1 = *reinterpret_cast<const float4*>(&sB[kk][tx * 4 + 64]);
            float a[8] = {a0.x, a0.y, a0.z, a0.w, a1.x, a1.y, a1.z, a1.w};
            float b[8] = {b0.x, b0.y, b0.z, b0.w, b1.x, b1.y, b1.z, b1.w};
            #pragma unroll
            for (int i = 0; i < 8; ++i)
                #pragma unroll
                for (int j = 0; j < 8; ++j)
                    acc[i][j] = fmaf(a[i], b[j], acc[i][j]);
        }
    }

    #pragma unroll
    for (int i = 0; i < 8; ++i) {
        int t = m0 + ty * 8 + i;
        float4 v0 = make_float4(acc[i][0], acc[i][1], acc[i][2], acc[i][3]);
        float4 v1 = make_float4(acc[i][4], acc[i][5], acc[i][6], acc[i][7]);
        *reinterpret_cast<float4*>(Cmat + (size_t)t * C_DIM + n0 + tx * 4)      = v0;
        *reinterpret_cast<float4*>(Cmat + (size_t)t * C_DIM + n0 + 64 + tx * 4) = v1;
    }
}

// ---------------------------------------------------------------------------
extern "C" void kernel_launch(void* const* d_in, const int* in_sizes, int n_in,
                              void* d_out, int out_size, void* d_ws, size_t ws_size,
                              hipStream_t stream) {
    const float* x  = (const float*)d_in[0];
    const float* Wq = (const float*)d_in[1];
    const float* Wk = (const float*)d_in[2];
    const float* Wv = (const float*)d_in[3];
    const float* Wo = (const float*)d_in[4];

    float* ws   = (float*)d_ws;
    float* cosT = ws;                       // 131072
    float* sinT = cosT + 131072;            // 131072
    float* Qh   = sinT + 131072;            // 6291456
    float* Kh   = Qh   + 6291456;           // 2097152
    float* Vh   = Kh   + 2097152;           // 2097152
    float* AO   = Vh   + 2097152;           // 6291456
    float* out  = (float*)d_out;

    rope_table<<<dim3(2048),    dim3(64),  0, stream>>>(cosT, sinT);
    qkv_gemm  <<<dim3(40, 16),  dim3(256), 0, stream>>>(x, Wq, Wk, Wv, Qh, Kh, Vh);
    rope_apply<<<dim3(2048, 8), dim3(256), 0, stream>>>(Qh, Kh, cosT, sinT);
    attn_kernel<<<dim3(32, 24), dim3(256), 0, stream>>>(Qh, Kh, Vh, AO);
    out_gemm  <<<dim3(24, 16),  dim3(256), 0, stream>>>(AO, Wo, out);
}

// Round 2
// 672.904 us; speedup vs baseline: 3.7189x; 3.7189x over previous
//
#include <hip/hip_runtime.h>
#include <cstdint>

#define T_SEQ 2048
#define C_DIM 3072
#define NH    24
#define NKV   8
#define HD    128

typedef short  bf16x8 __attribute__((ext_vector_type(8)));
typedef float  f32x4  __attribute__((ext_vector_type(4)));

__device__ __forceinline__ ushort f2bf(float f) {
    union { float f; uint32_t u; } v; v.f = f;
    uint32_t r = (v.u + 0x7FFF + ((v.u >> 16) & 1)) >> 16;
    return (ushort)r;
}

__device__ __forceinline__ void gll16(const void* g, void* lds) {
    __builtin_amdgcn_global_load_lds(
        (const __attribute__((address_space(1))) uint32_t*)g,
        (__attribute__((address_space(3))) uint32_t*)lds, 16, 0, 0);
}

// ---------------------------------------------------------------------------
// RoPE tables (fp32): cosT/sinT [2048][64]
// ---------------------------------------------------------------------------
__global__ __launch_bounds__(64) void rope_table(float* __restrict__ cosT,
                                                 float* __restrict__ sinT) {
    int t = blockIdx.x;
    int j = threadIdx.x;
    float inv = powf(10000.0f, -(float)j * (1.0f / 64.0f));
    float ang = (float)t * inv;
    cosT[t * 64 + j] = cosf(ang);
    sinT[t * 64 + j] = sinf(ang);
}

// ---------------------------------------------------------------------------
// x fp32 -> bf16 (row-major unchanged)
// ---------------------------------------------------------------------------
__global__ __launch_bounds__(256) void convert_x(const float* __restrict__ x,
                                                 ushort* __restrict__ xb) {
    int i = blockIdx.x * 256 + threadIdx.x;
    int stride = gridDim.x * 256;
    const int n4 = (T_SEQ * C_DIM) / 4;
    for (; i < n4; i += stride) {
        float4 v = ((const float4*)x)[i];
        ushort4 o;
        o.x = f2bf(v.x); o.y = f2bf(v.y); o.z = f2bf(v.z); o.w = f2bf(v.w);
        ((ushort4*)xb)[i] = o;
    }
}

// ---------------------------------------------------------------------------
// W [3072][ldN] fp32  ->  dst [ldN][3072] bf16  (n-major transpose+convert)
// ---------------------------------------------------------------------------
__global__ __launch_bounds__(256) void transpose_w(const float* __restrict__ src,
                                                   ushort* __restrict__ dst,
                                                   int ldN) {
    __shared__ float sT[64][65];
    const int n0 = blockIdx.x * 64;
    const int k0 = blockIdx.y * 64;
    const int r  = threadIdx.x >> 4;
    const int c4 = (threadIdx.x & 15) * 4;
    #pragma unroll
    for (int i = 0; i < 4; ++i) {
        int kk = r + i * 16;
        float4 v = *(const float4*)&src[(size_t)(k0 + kk) * ldN + n0 + c4];
        sT[kk][c4 + 0] = v.x; sT[kk][c4 + 1] = v.y;
        sT[kk][c4 + 2] = v.z; sT[kk][c4 + 3] = v.w;
    }
    __syncthreads();
    #pragma unroll
    for (int i = 0; i < 4; ++i) {
        int nn = r + i * 16;
        ushort4 o;
        o.x = f2bf(sT[c4 + 0][nn]); o.y = f2bf(sT[c4 + 1][nn]);
        o.z = f2bf(sT[c4 + 2][nn]); o.w = f2bf(sT[c4 + 3][nn]);
        *(ushort4*)&dst[(size_t)(n0 + nn) * C_DIM + k0 + c4] = o;
    }
}

// ---------------------------------------------------------------------------
// QKV GEMM (bf16 MFMA): xb[2048,3072] @ WbT'[5120,3072] (n-major)
// n-tile 128 == one head. bx<24: Q (+RoPE), 24..31: K (+RoPE), 32..39: V
// (transposed write -> Vt[head][d][t]).
// Block 256 thr = 4 waves; wave w owns rows w*32..+31, all 128 cols.
// LDS: linear row-major [128][64] bf16, XOR-swizzled 16B chunks (chunk^row&7),
// staged via global_load_lds w/ pre-swizzled global source (both-sides rule).
// ---------------------------------------------------------------------------
__global__ __launch_bounds__(256) void qkv_gemm_mfma(
    const ushort* __restrict__ xb, const ushort* __restrict__ WbT,
    const float* __restrict__ cosT, const float* __restrict__ sinT,
    ushort* __restrict__ Qb, ushort* __restrict__ Kb, ushort* __restrict__ Vt) {

    __shared__ ushort sA[128 * 64];
    __shared__ ushort sB[128 * 64];

    const int bx = blockIdx.x;      // 0..39
    const int by = blockIdx.y;      // 0..15
    const int tid = threadIdx.x;
    const int w = tid >> 6, l = tid & 63, g = l >> 4, c = l & 15;
    const int m0 = by * 128, n0 = bx * 128;

    f32x4 acc[2][8];
    #pragma unroll
    for (int m = 0; m < 2; ++m)
        #pragma unroll
        for (int n = 0; n < 8; ++n) acc[m][n] = {0.f, 0.f, 0.f, 0.f};

    const int ch  = (w * 4) * 64 + l;          // base chunk id for u=0
    for (int k0 = 0; k0 < C_DIM; k0 += 64) {
        __syncthreads();
        #pragma unroll
        for (int u = 0; u < 4; ++u) {
            int chu = ch + u * 64;
            int row = chu >> 3, sub = chu & 7;
            int sc  = sub ^ (row & 7);
            gll16(xb  + (size_t)(m0 + row) * C_DIM + k0 + sc * 8, &sA[(w * 4 + u) * 512]);
            gll16(WbT + (size_t)(n0 + row) * C_DIM + k0 + sc * 8, &sB[(w * 4 + u) * 512]);
        }
        __syncthreads();

        #pragma unroll
        for (int kc = 0; kc < 2; ++kc) {
            bf16x8 a[2], b[8];
            #pragma unroll
            for (int m = 0; m < 2; ++m) {
                int row = w * 32 + m * 16 + c;
                int chp = (kc * 4 + g) ^ (row & 7);
                a[m] = *(const bf16x8*)&sA[row * 64 + chp * 8];
            }
            #pragma unroll
            for (int n = 0; n < 8; ++n) {
                int row = n * 16 + c;
                int chp = (kc * 4 + g) ^ (row & 7);
                b[n] = *(const bf16x8*)&sB[row * 64 + chp * 8];
            }
            #pragma unroll
            for (int m = 0; m < 2; ++m)
                #pragma unroll
                for (int n = 0; n < 8; ++n)
                    acc[m][n] = __builtin_amdgcn_mfma_f32_16x16x32_bf16(a[m], b[n], acc[m][n], 0, 0, 0);
        }
    }

    if (bx < 32) {
        // Q or K head with fused RoPE. acc col d = n*16+c (n<4 pairs with n+4).
        ushort* dst = (bx < 24) ? (Qb + (size_t)bx * T_SEQ * HD)
                                : (Kb + (size_t)(bx - 24) * T_SEQ * HD);
        #pragma unroll
        for (int m = 0; m < 2; ++m) {
            #pragma unroll
            for (int n = 0; n < 4; ++n) {
                #pragma unroll
                for (int r = 0; r < 4; ++r) {
                    int t = m0 + w * 32 + m * 16 + g * 4 + r;
                    int d = n * 16 + c;
                    float q1 = acc[m][n][r], q2 = acc[m][n + 4][r];
                    float cv = cosT[t * 64 + d], sv = sinT[t * 64 + d];
                    dst[(size_t)t * HD + d]      = f2bf(q1 * cv - q2 * sv);
                    dst[(size_t)t * HD + 64 + d] = f2bf(q2 * cv + q1 * sv);
                }
            }
        }
    } else {
        // V: write transposed Vt[head][d][t], pack 4 consecutive t per lane
        ushort* dst = Vt + (size_t)(bx - 32) * HD * T_SEQ;
        #pragma unroll
        for (int m = 0; m < 2; ++m) {
            #pragma unroll
            for (int n = 0; n < 8; ++n) {
                int d  = n * 16 + c;
                int t0 = m0 + w * 32 + m * 16 + g * 4;
                ushort4 pk;
                pk.x = f2bf(acc[m][n][0]); pk.y = f2bf(acc[m][n][1]);
                pk.z = f2bf(acc[m][n][2]); pk.w = f2bf(acc[m][n][3]);
                *(ushort4*)&dst[(size_t)d * T_SEQ + t0] = pk;
            }
        }
    }
}

// ---------------------------------------------------------------------------
// Flash attention, bf16 MFMA, GQA (kh = h/3), causal.
// grid (32 q-tiles, 24 heads), 4 waves; wave = 16 q-rows, full d=128.
// K/V read straight from L2 (512 KB/head, cache-resident). P goes through a
// per-wave padded LDS buffer to switch from D-layout to A-fragment layout.
// ---------------------------------------------------------------------------
__global__ __launch_bounds__(256) void attn_mfma(
    const ushort* __restrict__ Qb, const ushort* __restrict__ Kb,
    const ushort* __restrict__ Vt, ushort* __restrict__ AO) {

    __shared__ ushort sP[4][16][72];   // per-wave, pad 72 -> 2-way banks only

    const int qt = blockIdx.x, h = blockIdx.y;
    const int kh = h / 3;
    const int tid = threadIdx.x;
    const int w = tid >> 6, l = tid & 63, g = l >> 4, c = l & 15;

    const ushort* Qp = Qb + (size_t)h  * T_SEQ * HD;
    const ushort* Kp = Kb + (size_t)kh * T_SEQ * HD;
    const ushort* Vp = Vt + (size_t)kh * HD * T_SEQ;

    const int qrow = qt * 64 + w * 16 + c;      // A-operand row (QK^T)
    bf16x8 qf[4];
    #pragma unroll
    for (int kc = 0; kc < 4; ++kc)
        qf[kc] = *(const bf16x8*)&Qp[(size_t)qrow * HD + kc * 32 + g * 8];

    f32x4 o[8];
    #pragma unroll
    for (int n = 0; n < 8; ++n) o[n] = {0.f, 0.f, 0.f, 0.f};
    float m_run[4], l_run[4];
    #pragma unroll
    for (int r = 0; r < 4; ++r) { m_run[r] = -3.0e38f; l_run[r] = 0.f; }

    const float scale = 0.08838834764831845f;   // 1/sqrt(128)
    const int qrow_d = qt * 64 + w * 16 + g * 4;  // D-layout base row

    for (int kt = 0; kt <= qt; ++kt) {
        // ---- S = Q K^T ----
        f32x4 sacc[4];
        #pragma unroll
        for (int nt = 0; nt < 4; ++nt) sacc[nt] = {0.f, 0.f, 0.f, 0.f};
        #pragma unroll
        for (int nt = 0; nt < 4; ++nt) {
            #pragma unroll
            for (int kc = 0; kc < 4; ++kc) {
                bf16x8 kf = *(const bf16x8*)&Kp[(size_t)(kt * 64 + nt * 16 + c) * HD + kc * 32 + g * 8];
                sacc[nt] = __builtin_amdgcn_mfma_f32_16x16x32_bf16(qf[kc], kf, sacc[nt], 0, 0, 0);
            }
        }
        // ---- scale + causal + online softmax ----
        float p[4][4], pm[4];
        #pragma unroll
        for (int r = 0; r < 4; ++r) pm[r] = -3.0e38f;
        #pragma unroll
        for (int nt = 0; nt < 4; ++nt) {
            int key = kt * 64 + nt * 16 + c;
            #pragma unroll
            for (int r = 0; r < 4; ++r) {
                float s = sacc[nt][r] * scale;
                if (key > qrow_d + r) s = -3.0e38f;
                p[nt][r] = s;
                pm[r] = fmaxf(pm[r], s);
            }
        }
        #pragma unroll
        for (int r = 0; r < 4; ++r) {
            pm[r] = fmaxf(pm[r], __shfl_xor(pm[r], 1));
            pm[r] = fmaxf(pm[r], __shfl_xor(pm[r], 2));
            pm[r] = fmaxf(pm[r], __shfl_xor(pm[r], 4));
            pm[r] = fmaxf(pm[r], __shfl_xor(pm[r], 8));
        }
        float alpha[4], psum[4];
        #pragma unroll
        for (int r = 0; r < 4; ++r) {
            float mnew = fmaxf(m_run[r], pm[r]);
            alpha[r] = __expf(m_run[r] - mnew);
            m_run[r] = mnew;
            psum[r] = 0.f;
            #pragma unroll
            for (int nt = 0; nt < 4; ++nt) {
                float e = __expf(p[nt][r] - mnew);
                p[nt][r] = e;
                psum[r] += e;
            }
        }
        #pragma unroll
        for (int r = 0; r < 4; ++r) {
            psum[r] += __shfl_xor(psum[r], 1);
            psum[r] += __shfl_xor(psum[r], 2);
            psum[r] += __shfl_xor(psum[r], 4);
            psum[r] += __shfl_xor(psum[r], 8);
            l_run[r] = l_run[r] * alpha[r] + psum[r];
        }
        #pragma unroll
        for (int n = 0; n < 8; ++n) {
            f32x4 t = o[n];
            t[0] *= alpha[0]; t[1] *= alpha[1]; t[2] *= alpha[2]; t[3] *= alpha[3];
            o[n] = t;
        }
        // ---- P (D-layout) -> LDS -> A-fragment layout ----
        #pragma unroll
        for (int nt = 0; nt < 4; ++nt)
            #pragma unroll
            for (int r = 0; r < 4; ++r)
                sP[w][g * 4 + r][nt * 16 + c] = f2bf(p[nt][r]);
        // same-wave LDS ordering is in-order; no barrier needed
        #pragma unroll
        for (int kc2 = 0; kc2 < 2; ++kc2) {
            bf16x8 pa = *(const bf16x8*)&sP[w][c][kc2 * 32 + g * 8];
            #pragma unroll
            for (int n = 0; n < 8; ++n) {
                bf16x8 vf = *(const bf16x8*)&Vp[(size_t)(n * 16 + c) * T_SEQ + kt * 64 + kc2 * 32 + g * 8];
                o[n] = __builtin_amdgcn_mfma_f32_16x16x32_bf16(pa, vf, o[n], 0, 0, 0);
            }
        }
    }

    float inv[4];
    #pragma unroll
    for (int r = 0; r < 4; ++r) inv[r] = 1.0f / l_run[r];
    #pragma unroll
    for (int n = 0; n < 8; ++n)
        #pragma unroll
        for (int r = 0; r < 4; ++r) {
            int t = qrow_d + r;
            AO[(size_t)t * C_DIM + h * HD + n * 16 + c] = f2bf(o[n][r] * inv[r]);
        }
}

// ---------------------------------------------------------------------------
// Output projection: AO[2048,3072] bf16 @ WoT[3072,3072] (n-major) -> fp32 out
// ---------------------------------------------------------------------------
__global__ __launch_bounds__(256) void out_gemm_mfma(
    const ushort* __restrict__ Ab, const ushort* __restrict__ BT,
    float* __restrict__ outp) {

    __shared__ ushort sA[128 * 64];
    __shared__ ushort sB[128 * 64];

    const int bx = blockIdx.x;      // 0..23
    const int by = blockIdx.y;      // 0..15
    const int tid = threadIdx.x;
    const int w = tid >> 6, l = tid & 63, g = l >> 4, c = l & 15;
    const int m0 = by * 128, n0 = bx * 128;

    f32x4 acc[2][8];
    #pragma unroll
    for (int m = 0; m < 2; ++m)
        #pragma unroll
        for (int n = 0; n < 8; ++n) acc[m][n] = {0.f, 0.f, 0.f, 0.f};

    const int ch = (w * 4) * 64 + l;
    for (int k0 = 0; k0 < C_DIM; k0 += 64) {
        __syncthreads();
        #pragma unroll
        for (int u = 0; u < 4; ++u) {
            int chu = ch + u * 64;
            int row = chu >> 3, sub = chu & 7;
            int sc  = sub ^ (row & 7);
            gll16(Ab + (size_t)(m0 + row) * C_DIM + k0 + sc * 8, &sA[(w * 4 + u) * 512]);
            gll16(BT + (size_t)(n0 + row) * C_DIM + k0 + sc * 8, &sB[(w * 4 + u) * 512]);
        }
        __syncthreads();

        #pragma unroll
        for (int kc = 0; kc < 2; ++kc) {
            bf16x8 a[2], b[8];
            #pragma unroll
            for (int m = 0; m < 2; ++m) {
                int row = w * 32 + m * 16 + c;
                int chp = (kc * 4 + g) ^ (row & 7);
                a[m] = *(const bf16x8*)&sA[row * 64 + chp * 8];
            }
            #pragma unroll
            for (int n = 0; n < 8; ++n) {
                int row = n * 16 + c;
                int chp = (kc * 4 + g) ^ (row & 7);
                b[n] = *(const bf16x8*)&sB[row * 64 + chp * 8];
            }
            #pragma unroll
            for (int m = 0; m < 2; ++m)
                #pragma unroll
                for (int n = 0; n < 8; ++n)
                    acc[m][n] = __builtin_amdgcn_mfma_f32_16x16x32_bf16(a[m], b[n], acc[m][n], 0, 0, 0);
        }
    }

    #pragma unroll
    for (int m = 0; m < 2; ++m)
        #pragma unroll
        for (int n = 0; n < 8; ++n)
            #pragma unroll
            for (int r = 0; r < 4; ++r) {
                int t = m0 + w * 32 + m * 16 + g * 4 + r;
                outp[(size_t)t * C_DIM + n0 + n * 16 + c] = acc[m][n][r];
            }
}

// ---------------------------------------------------------------------------
extern "C" void kernel_launch(void* const* d_in, const int* in_sizes, int n_in,
                              void* d_out, int out_size, void* d_ws, size_t ws_size,
                              hipStream_t stream) {
    const float* x  = (const float*)d_in[0];
    const float* Wq = (const float*)d_in[1];
    const float* Wk = (const float*)d_in[2];
    const float* Wv = (const float*)d_in[3];
    const float* Wo = (const float*)d_in[4];

    char* ws = (char*)d_ws;
    float*  cosT = (float*)ws;                         ws += 2048 * 64 * 4;
    float*  sinT = (float*)ws;                         ws += 2048 * 64 * 4;
    ushort* WbT  = (ushort*)ws;                        ws += (size_t)5120 * 3072 * 2;
    ushort* WoT  = (ushort*)ws;                        ws += (size_t)3072 * 3072 * 2;
    ushort* Qb   = (ushort*)ws;                        ws += (size_t)NH  * T_SEQ * HD * 2;
    ushort* Kb   = (ushort*)ws;                        ws += (size_t)NKV * T_SEQ * HD * 2;
    ushort* Vt   = (ushort*)ws;                        ws += (size_t)NKV * T_SEQ * HD * 2;
    ushort* xb   = (ushort*)ws;                        // 2048*3072*2
    ushort* AO   = xb;                                 // alias: xb dead after qkv_gemm
    float*  out  = (float*)d_out;

    rope_table <<<dim3(2048),   dim3(64),  0, stream>>>(cosT, sinT);
    convert_x  <<<dim3(2048),   dim3(256), 0, stream>>>(x, xb);
    transpose_w<<<dim3(48, 48), dim3(256), 0, stream>>>(Wq, WbT,                       3072);
    transpose_w<<<dim3(16, 48), dim3(256), 0, stream>>>(Wk, WbT + (size_t)3072 * 3072, 1024);
    transpose_w<<<dim3(16, 48), dim3(256), 0, stream>>>(Wv, WbT + (size_t)4096 * 3072, 1024);
    transpose_w<<<dim3(48, 48), dim3(256), 0, stream>>>(Wo, WoT,                       3072);

    qkv_gemm_mfma<<<dim3(40, 16), dim3(256), 0, stream>>>(xb, WbT, cosT, sinT, Qb, Kb, Vt);
    attn_mfma    <<<dim3(32, 24), dim3(256), 0, stream>>>(Qb, Kb, Vt, AO);
    out_gemm_mfma<<<dim3(24, 16), dim3(256), 0, stream>>>(AO, WoT, out);
}

// Round 3
// 482.237 us; speedup vs baseline: 5.1892x; 1.3954x over previous
//
#include <hip/hip_runtime.h>
#include <cstdint>

#define T_SEQ 2048
#define C_DIM 3072
#define NH    24
#define NKV   8
#define HD    128

typedef short  bf16x8 __attribute__((ext_vector_type(8)));
typedef float  f32x4  __attribute__((ext_vector_type(4)));

__device__ __forceinline__ ushort f2bf(float f) {
    union { float f; uint32_t u; } v; v.f = f;
    uint32_t r = (v.u + 0x7FFF + ((v.u >> 16) & 1)) >> 16;
    return (ushort)r;
}

__device__ __forceinline__ void gll16(const void* g, void* lds) {
    __builtin_amdgcn_global_load_lds(
        (const __attribute__((address_space(1))) uint32_t*)g,
        (__attribute__((address_space(3))) uint32_t*)lds, 16, 0, 0);
}

// ---------------------------------------------------------------------------
// RoPE tables (fp32): cosT/sinT [2048][64]
// ---------------------------------------------------------------------------
__global__ __launch_bounds__(64) void rope_table(float* __restrict__ cosT,
                                                 float* __restrict__ sinT) {
    int t = blockIdx.x;
    int j = threadIdx.x;
    float inv = powf(10000.0f, -(float)j * (1.0f / 64.0f));
    float ang = (float)t * inv;
    cosT[t * 64 + j] = cosf(ang);
    sinT[t * 64 + j] = sinf(ang);
}

// ---------------------------------------------------------------------------
// x fp32 -> bf16
// ---------------------------------------------------------------------------
__global__ __launch_bounds__(256) void convert_x(const float* __restrict__ x,
                                                 ushort* __restrict__ xb) {
    int i = blockIdx.x * 256 + threadIdx.x;
    int stride = gridDim.x * 256;
    const int n4 = (T_SEQ * C_DIM) / 4;
    for (; i < n4; i += stride) {
        float4 v = ((const float4*)x)[i];
        ushort4 o;
        o.x = f2bf(v.x); o.y = f2bf(v.y); o.z = f2bf(v.z); o.w = f2bf(v.w);
        ((ushort4*)xb)[i] = o;
    }
}

// ---------------------------------------------------------------------------
// W [3072][ldN] fp32 -> dst [ldN][3072] bf16 (n-major transpose+convert)
// ---------------------------------------------------------------------------
__global__ __launch_bounds__(256) void transpose_w(const float* __restrict__ src,
                                                   ushort* __restrict__ dst,
                                                   int ldN) {
    __shared__ float sT[64][65];
    const int n0 = blockIdx.x * 64;
    const int k0 = blockIdx.y * 64;
    const int r  = threadIdx.x >> 4;
    const int c4 = (threadIdx.x & 15) * 4;
    #pragma unroll
    for (int i = 0; i < 4; ++i) {
        int kk = r + i * 16;
        float4 v = *(const float4*)&src[(size_t)(k0 + kk) * ldN + n0 + c4];
        sT[kk][c4 + 0] = v.x; sT[kk][c4 + 1] = v.y;
        sT[kk][c4 + 2] = v.z; sT[kk][c4 + 3] = v.w;
    }
    __syncthreads();
    #pragma unroll
    for (int i = 0; i < 4; ++i) {
        int nn = r + i * 16;
        ushort4 o;
        o.x = f2bf(sT[c4 + 0][nn]); o.y = f2bf(sT[c4 + 1][nn]);
        o.z = f2bf(sT[c4 + 2][nn]); o.w = f2bf(sT[c4 + 3][nn]);
        *(ushort4*)&dst[(size_t)(n0 + nn) * C_DIM + k0 + c4] = o;
    }
}

// ---------------------------------------------------------------------------
// QKV GEMM (bf16 MFMA) with fused RoPE epilogue. Unchanged from round 2.
// ---------------------------------------------------------------------------
__global__ __launch_bounds__(256) void qkv_gemm_mfma(
    const ushort* __restrict__ xb, const ushort* __restrict__ WbT,
    const float* __restrict__ cosT, const float* __restrict__ sinT,
    ushort* __restrict__ Qb, ushort* __restrict__ Kb, ushort* __restrict__ Vt) {

    __shared__ ushort sA[128 * 64];
    __shared__ ushort sB[128 * 64];

    const int bx = blockIdx.x;      // 0..39
    const int by = blockIdx.y;      // 0..15
    const int tid = threadIdx.x;
    const int w = tid >> 6, l = tid & 63, g = l >> 4, c = l & 15;
    const int m0 = by * 128, n0 = bx * 128;

    f32x4 acc[2][8];
    #pragma unroll
    for (int m = 0; m < 2; ++m)
        #pragma unroll
        for (int n = 0; n < 8; ++n) acc[m][n] = {0.f, 0.f, 0.f, 0.f};

    const int ch = (w * 4) * 64 + l;
    for (int k0 = 0; k0 < C_DIM; k0 += 64) {
        __syncthreads();
        #pragma unroll
        for (int u = 0; u < 4; ++u) {
            int chu = ch + u * 64;
            int row = chu >> 3, sub = chu & 7;
            int sc  = sub ^ (row & 7);
            gll16(xb  + (size_t)(m0 + row) * C_DIM + k0 + sc * 8, &sA[(w * 4 + u) * 512]);
            gll16(WbT + (size_t)(n0 + row) * C_DIM + k0 + sc * 8, &sB[(w * 4 + u) * 512]);
        }
        __syncthreads();

        #pragma unroll
        for (int kc = 0; kc < 2; ++kc) {
            bf16x8 a[2], b[8];
            #pragma unroll
            for (int m = 0; m < 2; ++m) {
                int row = w * 32 + m * 16 + c;
                int chp = (kc * 4 + g) ^ (row & 7);
                a[m] = *(const bf16x8*)&sA[row * 64 + chp * 8];
            }
            #pragma unroll
            for (int n = 0; n < 8; ++n) {
                int row = n * 16 + c;
                int chp = (kc * 4 + g) ^ (row & 7);
                b[n] = *(const bf16x8*)&sB[row * 64 + chp * 8];
            }
            #pragma unroll
            for (int m = 0; m < 2; ++m)
                #pragma unroll
                for (int n = 0; n < 8; ++n)
                    acc[m][n] = __builtin_amdgcn_mfma_f32_16x16x32_bf16(a[m], b[n], acc[m][n], 0, 0, 0);
        }
    }

    if (bx < 32) {
        ushort* dst = (bx < 24) ? (Qb + (size_t)bx * T_SEQ * HD)
                                : (Kb + (size_t)(bx - 24) * T_SEQ * HD);
        #pragma unroll
        for (int m = 0; m < 2; ++m) {
            #pragma unroll
            for (int n = 0; n < 4; ++n) {
                #pragma unroll
                for (int r = 0; r < 4; ++r) {
                    int t = m0 + w * 32 + m * 16 + g * 4 + r;
                    int d = n * 16 + c;
                    float q1 = acc[m][n][r], q2 = acc[m][n + 4][r];
                    float cv = cosT[t * 64 + d], sv = sinT[t * 64 + d];
                    dst[(size_t)t * HD + d]      = f2bf(q1 * cv - q2 * sv);
                    dst[(size_t)t * HD + 64 + d] = f2bf(q2 * cv + q1 * sv);
                }
            }
        }
    } else {
        ushort* dst = Vt + (size_t)(bx - 32) * HD * T_SEQ;
        #pragma unroll
        for (int m = 0; m < 2; ++m) {
            #pragma unroll
            for (int n = 0; n < 8; ++n) {
                int d  = n * 16 + c;
                int t0 = m0 + w * 32 + m * 16 + g * 4;
                ushort4 pk;
                pk.x = f2bf(acc[m][n][0]); pk.y = f2bf(acc[m][n][1]);
                pk.z = f2bf(acc[m][n][2]); pk.w = f2bf(acc[m][n][3]);
                *(ushort4*)&dst[(size_t)d * T_SEQ + t0] = pk;
            }
        }
    }
}

// ---------------------------------------------------------------------------
// Flash attention v2: LDS-staged K/V (double-buffered, global_load_lds,
// XOR-swizzled), 4 waves x 16 q-rows, GQA causal.
// LDS: sK[2][64][128] (16KB ea), sV[2][128][64] (16KB ea), sP 9KB = 73KB.
// One barrier per kt iteration; kt+1 loads issued before kt compute.
// ---------------------------------------------------------------------------
__global__ __launch_bounds__(256) void attn_mfma(
    const ushort* __restrict__ Qb, const ushort* __restrict__ Kb,
    const ushort* __restrict__ Vt, ushort* __restrict__ AO) {

    __shared__ ushort sK[2][64 * 128];
    __shared__ ushort sV[2][128 * 64];
    __shared__ ushort sP[4][16][72];

    const int qt = (int)(gridDim.x - 1 - blockIdx.x);   // long blocks first
    const int h  = blockIdx.y;
    const int kh = h / 3;
    const int tid = threadIdx.x;
    const int w = tid >> 6, l = tid & 63, g = l >> 4, c = l & 15;

    const ushort* Qp = Qb + (size_t)h  * T_SEQ * HD;
    const ushort* Kp = Kb + (size_t)kh * T_SEQ * HD;
    const ushort* Vp = Vt + (size_t)kh * HD * T_SEQ;

    const int qrow = qt * 64 + w * 16 + c;
    bf16x8 qf[4];
    #pragma unroll
    for (int kc = 0; kc < 4; ++kc)
        qf[kc] = *(const bf16x8*)&Qp[(size_t)qrow * HD + kc * 32 + g * 8];

    f32x4 o[8];
    #pragma unroll
    for (int n = 0; n < 8; ++n) o[n] = {0.f, 0.f, 0.f, 0.f};
    float m_run[4], l_run[4];
    #pragma unroll
    for (int r = 0; r < 4; ++r) { m_run[r] = -3.0e38f; l_run[r] = 0.f; }

    const float scale = 0.08838834764831845f;
    const int qrow_d = qt * 64 + w * 16 + g * 4;

    // ---- staging helper (as lambda-free macro-ish blocks) ----
    // K tile: 1024 chunks of 16B; chunk = (w*4+u)*64 + l; row=chunk>>4 (16/row)
    // V tile: 1024 chunks; row=chunk>>3 (8/row)
    #define STAGE_KV(ktile, buf)                                                     \
        {                                                                            \
            _Pragma("unroll")                                                        \
            for (int u = 0; u < 4; ++u) {                                            \
                int chunk = (w * 4 + u) * 64 + l;                                    \
                int row = chunk >> 4;                                                \
                int sub = (chunk & 15) ^ (row & 7);                                  \
                gll16(Kp + (size_t)((ktile) * 64 + row) * HD + sub * 8,              \
                      &sK[buf][(w * 4 + u) * 512]);                                  \
            }                                                                        \
            _Pragma("unroll")                                                        \
            for (int u = 0; u < 4; ++u) {                                            \
                int chunk = (w * 4 + u) * 64 + l;                                    \
                int row = chunk >> 3;                                                \
                int sub = (chunk & 7) ^ (row & 7);                                   \
                gll16(Vp + (size_t)row * T_SEQ + (ktile) * 64 + sub * 8,             \
                      &sV[buf][(w * 4 + u) * 512]);                                  \
            }                                                                        \
        }

    int cur = 0;
    STAGE_KV(0, 0);
    __syncthreads();

    for (int kt = 0; kt <= qt; ++kt) {
        if (kt < qt) STAGE_KV(kt + 1, cur ^ 1);

        // ---- S = Q K^T from sK[cur] ----
        f32x4 sacc[4];
        #pragma unroll
        for (int nt = 0; nt < 4; ++nt) sacc[nt] = {0.f, 0.f, 0.f, 0.f};
        const ushort* sKc = &sK[cur][0];
        __builtin_amdgcn_s_setprio(1);
        #pragma unroll
        for (int nt = 0; nt < 4; ++nt) {
            int row = nt * 16 + c;
            #pragma unroll
            for (int kc = 0; kc < 4; ++kc) {
                int chp = (kc * 4 + g) ^ (row & 7);
                bf16x8 kf = *(const bf16x8*)&sKc[row * 128 + chp * 8];
                sacc[nt] = __builtin_amdgcn_mfma_f32_16x16x32_bf16(qf[kc], kf, sacc[nt], 0, 0, 0);
            }
        }
        __builtin_amdgcn_s_setprio(0);

        // ---- scale + causal + online softmax ----
        float p[4][4], pm[4];
        #pragma unroll
        for (int r = 0; r < 4; ++r) pm[r] = -3.0e38f;
        #pragma unroll
        for (int nt = 0; nt < 4; ++nt) {
            int key = kt * 64 + nt * 16 + c;
            #pragma unroll
            for (int r = 0; r < 4; ++r) {
                float s = sacc[nt][r] * scale;
                if (key > qrow_d + r) s = -3.0e38f;
                p[nt][r] = s;
                pm[r] = fmaxf(pm[r], s);
            }
        }
        #pragma unroll
        for (int r = 0; r < 4; ++r) {
            pm[r] = fmaxf(pm[r], __shfl_xor(pm[r], 1));
            pm[r] = fmaxf(pm[r], __shfl_xor(pm[r], 2));
            pm[r] = fmaxf(pm[r], __shfl_xor(pm[r], 4));
            pm[r] = fmaxf(pm[r], __shfl_xor(pm[r], 8));
        }
        float alpha[4], psum[4];
        #pragma unroll
        for (int r = 0; r < 4; ++r) {
            float mnew = fmaxf(m_run[r], pm[r]);
            alpha[r] = __expf(m_run[r] - mnew);
            m_run[r] = mnew;
            psum[r] = 0.f;
            #pragma unroll
            for (int nt = 0; nt < 4; ++nt) {
                float e = __expf(p[nt][r] - mnew);
                p[nt][r] = e;
                psum[r] += e;
            }
        }
        #pragma unroll
        for (int r = 0; r < 4; ++r) {
            psum[r] += __shfl_xor(psum[r], 1);
            psum[r] += __shfl_xor(psum[r], 2);
            psum[r] += __shfl_xor(psum[r], 4);
            psum[r] += __shfl_xor(psum[r], 8);
            l_run[r] = l_run[r] * alpha[r] + psum[r];
        }
        #pragma unroll
        for (int n = 0; n < 8; ++n) {
            f32x4 t = o[n];
            t[0] *= alpha[0]; t[1] *= alpha[1]; t[2] *= alpha[2]; t[3] *= alpha[3];
            o[n] = t;
        }

        // ---- P (D-layout) -> per-wave LDS -> A-fragment layout ----
        #pragma unroll
        for (int nt = 0; nt < 4; ++nt)
            #pragma unroll
            for (int r = 0; r < 4; ++r)
                sP[w][g * 4 + r][nt * 16 + c] = f2bf(p[nt][r]);

        // ---- PV from sV[cur] ----
        const ushort* sVc = &sV[cur][0];
        __builtin_amdgcn_s_setprio(1);
        #pragma unroll
        for (int kc2 = 0; kc2 < 2; ++kc2) {
            bf16x8 pa = *(const bf16x8*)&sP[w][c][kc2 * 32 + g * 8];
            #pragma unroll
            for (int n = 0; n < 8; ++n) {
                int row = n * 16 + c;
                int chp = (kc2 * 4 + g) ^ (row & 7);
                bf16x8 vf = *(const bf16x8*)&sVc[row * 64 + chp * 8];
                o[n] = __builtin_amdgcn_mfma_f32_16x16x32_bf16(pa, vf, o[n], 0, 0, 0);
            }
        }
        __builtin_amdgcn_s_setprio(0);

        __syncthreads();   // all reads of buf[cur] done; kt+1 loads drained
        cur ^= 1;
    }
    #undef STAGE_KV

    float inv[4];
    #pragma unroll
    for (int r = 0; r < 4; ++r) inv[r] = 1.0f / l_run[r];
    #pragma unroll
    for (int n = 0; n < 8; ++n)
        #pragma unroll
        for (int r = 0; r < 4; ++r) {
            int t = qrow_d + r;
            AO[(size_t)t * C_DIM + h * HD + n * 16 + c] = f2bf(o[n][r] * inv[r]);
        }
}

// ---------------------------------------------------------------------------
// Output projection: AO[2048,3072] bf16 @ WoT (n-major) -> fp32 out
// ---------------------------------------------------------------------------
__global__ __launch_bounds__(256) void out_gemm_mfma(
    const ushort* __restrict__ Ab, const ushort* __restrict__ BT,
    float* __restrict__ outp) {

    __shared__ ushort sA[128 * 64];
    __shared__ ushort sB[128 * 64];

    const int bx = blockIdx.x;
    const int by = blockIdx.y;
    const int tid = threadIdx.x;
    const int w = tid >> 6, l = tid & 63, g = l >> 4, c = l & 15;
    const int m0 = by * 128, n0 = bx * 128;

    f32x4 acc[2][8];
    #pragma unroll
    for (int m = 0; m < 2; ++m)
        #pragma unroll
        for (int n = 0; n < 8; ++n) acc[m][n] = {0.f, 0.f, 0.f, 0.f};

    const int ch = (w * 4) * 64 + l;
    for (int k0 = 0; k0 < C_DIM; k0 += 64) {
        __syncthreads();
        #pragma unroll
        for (int u = 0; u < 4; ++u) {
            int chu = ch + u * 64;
            int row = chu >> 3, sub = chu & 7;
            int sc  = sub ^ (row & 7);
            gll16(Ab + (size_t)(m0 + row) * C_DIM + k0 + sc * 8, &sA[(w * 4 + u) * 512]);
            gll16(BT + (size_t)(n0 + row) * C_DIM + k0 + sc * 8, &sB[(w * 4 + u) * 512]);
        }
        __syncthreads();

        #pragma unroll
        for (int kc = 0; kc < 2; ++kc) {
            bf16x8 a[2], b[8];
            #pragma unroll
            for (int m = 0; m < 2; ++m) {
                int row = w * 32 + m * 16 + c;
                int chp = (kc * 4 + g) ^ (row & 7);
                a[m] = *(const bf16x8*)&sA[row * 64 + chp * 8];
            }
            #pragma unroll
            for (int n = 0; n < 8; ++n) {
                int row = n * 16 + c;
                int chp = (kc * 4 + g) ^ (row & 7);
                b[n] = *(const bf16x8*)&sB[row * 64 + chp * 8];
            }
            #pragma unroll
            for (int m = 0; m < 2; ++m)
                #pragma unroll
                for (int n = 0; n < 8; ++n)
                    acc[m][n] = __builtin_amdgcn_mfma_f32_16x16x32_bf16(a[m], b[n], acc[m][n], 0, 0, 0);
        }
    }

    #pragma unroll
    for (int m = 0; m < 2; ++m)
        #pragma unroll
        for (int n = 0; n < 8; ++n)
            #pragma unroll
            for (int r = 0; r < 4; ++r) {
                int t = m0 + w * 32 + m * 16 + g * 4 + r;
                outp[(size_t)t * C_DIM + n0 + n * 16 + c] = acc[m][n][r];
            }
}

// ---------------------------------------------------------------------------
extern "C" void kernel_launch(void* const* d_in, const int* in_sizes, int n_in,
                              void* d_out, int out_size, void* d_ws, size_t ws_size,
                              hipStream_t stream) {
    const float* x  = (const float*)d_in[0];
    const float* Wq = (const float*)d_in[1];
    const float* Wk = (const float*)d_in[2];
    const float* Wv = (const float*)d_in[3];
    const float* Wo = (const float*)d_in[4];

    char* ws = (char*)d_ws;
    float*  cosT = (float*)ws;                         ws += 2048 * 64 * 4;
    float*  sinT = (float*)ws;                         ws += 2048 * 64 * 4;
    ushort* WbT  = (ushort*)ws;                        ws += (size_t)5120 * 3072 * 2;
    ushort* WoT  = (ushort*)ws;                        ws += (size_t)3072 * 3072 * 2;
    ushort* Qb   = (ushort*)ws;                        ws += (size_t)NH  * T_SEQ * HD * 2;
    ushort* Kb   = (ushort*)ws;                        ws += (size_t)NKV * T_SEQ * HD * 2;
    ushort* Vt   = (ushort*)ws;                        ws += (size_t)NKV * T_SEQ * HD * 2;
    ushort* xb   = (ushort*)ws;                        // 2048*3072*2
    ushort* AO   = xb;                                 // alias: xb dead after qkv_gemm
    float*  out  = (float*)d_out;

    rope_table <<<dim3(2048),   dim3(64),  0, stream>>>(cosT, sinT);
    convert_x  <<<dim3(2048),   dim3(256), 0, stream>>>(x, xb);
    transpose_w<<<dim3(48, 48), dim3(256), 0, stream>>>(Wq, WbT,                       3072);
    transpose_w<<<dim3(16, 48), dim3(256), 0, stream>>>(Wk, WbT + (size_t)3072 * 3072, 1024);
    transpose_w<<<dim3(16, 48), dim3(256), 0, stream>>>(Wv, WbT + (size_t)4096 * 3072, 1024);
    transpose_w<<<dim3(48, 48), dim3(256), 0, stream>>>(Wo, WoT,                       3072);

    qkv_gemm_mfma<<<dim3(40, 16), dim3(256), 0, stream>>>(xb, WbT, cosT, sinT, Qb, Kb, Vt);
    attn_mfma    <<<dim3(32, 24), dim3(256), 0, stream>>>(Qb, Kb, Vt, AO);
    out_gemm_mfma<<<dim3(24, 16), dim3(256), 0, stream>>>(AO, WoT, out);
}

// Round 4
// 453.310 us; speedup vs baseline: 5.5204x; 1.0638x over previous
//
#include <hip/hip_runtime.h>
#include <cstdint>

#define T_SEQ 2048
#define C_DIM 3072
#define NH    24
#define NKV   8
#define HD    128

typedef short  bf16x8 __attribute__((ext_vector_type(8)));
typedef float  f32x4  __attribute__((ext_vector_type(4)));

__device__ __forceinline__ ushort f2bf(float f) {
    union { float f; uint32_t u; } v; v.f = f;
    uint32_t r = (v.u + 0x7FFF + ((v.u >> 16) & 1)) >> 16;
    return (ushort)r;
}

__device__ __forceinline__ uint32_t cvtpk_bf16(float lo, float hi) {
    uint32_t r;
    asm("v_cvt_pk_bf16_f32 %0, %1, %2" : "=v"(r) : "v"(lo), "v"(hi));
    return r;
}

__device__ __forceinline__ float fast_exp2(float x) {
#if __has_builtin(__builtin_amdgcn_exp2f)
    return __builtin_amdgcn_exp2f(x);
#else
    return exp2f(x);
#endif
}

__device__ __forceinline__ void gll16(const void* g, void* lds) {
    __builtin_amdgcn_global_load_lds(
        (const __attribute__((address_space(1))) uint32_t*)g,
        (__attribute__((address_space(3))) uint32_t*)lds, 16, 0, 0);
}

// ---------------------------------------------------------------------------
// RoPE tables (fp32): cosT/sinT [2048][64]
// ---------------------------------------------------------------------------
__global__ __launch_bounds__(64) void rope_table(float* __restrict__ cosT,
                                                 float* __restrict__ sinT) {
    int t = blockIdx.x;
    int j = threadIdx.x;
    float inv = powf(10000.0f, -(float)j * (1.0f / 64.0f));
    float ang = (float)t * inv;
    cosT[t * 64 + j] = cosf(ang);
    sinT[t * 64 + j] = sinf(ang);
}

// ---------------------------------------------------------------------------
// x fp32 -> bf16
// ---------------------------------------------------------------------------
__global__ __launch_bounds__(256) void convert_x(const float* __restrict__ x,
                                                 ushort* __restrict__ xb) {
    int i = blockIdx.x * 256 + threadIdx.x;
    int stride = gridDim.x * 256;
    const int n4 = (T_SEQ * C_DIM) / 4;
    for (; i < n4; i += stride) {
        float4 v = ((const float4*)x)[i];
        ushort4 o;
        o.x = f2bf(v.x); o.y = f2bf(v.y); o.z = f2bf(v.z); o.w = f2bf(v.w);
        ((ushort4*)xb)[i] = o;
    }
}

// ---------------------------------------------------------------------------
// W [3072][ldN] fp32 -> dst [ldN][3072] bf16 (n-major transpose+convert)
// ---------------------------------------------------------------------------
__global__ __launch_bounds__(256) void transpose_w(const float* __restrict__ src,
                                                   ushort* __restrict__ dst,
                                                   int ldN) {
    __shared__ float sT[64][65];
    const int n0 = blockIdx.x * 64;
    const int k0 = blockIdx.y * 64;
    const int r  = threadIdx.x >> 4;
    const int c4 = (threadIdx.x & 15) * 4;
    #pragma unroll
    for (int i = 0; i < 4; ++i) {
        int kk = r + i * 16;
        float4 v = *(const float4*)&src[(size_t)(k0 + kk) * ldN + n0 + c4];
        sT[kk][c4 + 0] = v.x; sT[kk][c4 + 1] = v.y;
        sT[kk][c4 + 2] = v.z; sT[kk][c4 + 3] = v.w;
    }
    __syncthreads();
    #pragma unroll
    for (int i = 0; i < 4; ++i) {
        int nn = r + i * 16;
        ushort4 o;
        o.x = f2bf(sT[c4 + 0][nn]); o.y = f2bf(sT[c4 + 1][nn]);
        o.z = f2bf(sT[c4 + 2][nn]); o.w = f2bf(sT[c4 + 3][nn]);
        *(ushort4*)&dst[(size_t)(n0 + nn) * C_DIM + k0 + c4] = o;
    }
}

// ---------------------------------------------------------------------------
// QKV GEMM (bf16 MFMA) with fused RoPE epilogue.
// Q heads additionally scaled by 1/sqrt(128) * log2(e) (folded attn scale).
// ---------------------------------------------------------------------------
__global__ __launch_bounds__(256) void qkv_gemm_mfma(
    const ushort* __restrict__ xb, const ushort* __restrict__ WbT,
    const float* __restrict__ cosT, const float* __restrict__ sinT,
    ushort* __restrict__ Qb, ushort* __restrict__ Kb, ushort* __restrict__ Vt) {

    __shared__ ushort sA[128 * 64];
    __shared__ ushort sB[128 * 64];

    const int bx = blockIdx.x;      // 0..39
    const int by = blockIdx.y;      // 0..15
    const int tid = threadIdx.x;
    const int w = tid >> 6, l = tid & 63, g = l >> 4, c = l & 15;
    const int m0 = by * 128, n0 = bx * 128;

    f32x4 acc[2][8];
    #pragma unroll
    for (int m = 0; m < 2; ++m)
        #pragma unroll
        for (int n = 0; n < 8; ++n) acc[m][n] = {0.f, 0.f, 0.f, 0.f};

    const int ch = (w * 4) * 64 + l;
    for (int k0 = 0; k0 < C_DIM; k0 += 64) {
        __syncthreads();
        #pragma unroll
        for (int u = 0; u < 4; ++u) {
            int chu = ch + u * 64;
            int row = chu >> 3, sub = chu & 7;
            int sc  = sub ^ (row & 7);
            gll16(xb  + (size_t)(m0 + row) * C_DIM + k0 + sc * 8, &sA[(w * 4 + u) * 512]);
            gll16(WbT + (size_t)(n0 + row) * C_DIM + k0 + sc * 8, &sB[(w * 4 + u) * 512]);
        }
        __syncthreads();

        #pragma unroll
        for (int kc = 0; kc < 2; ++kc) {
            bf16x8 a[2], b[8];
            #pragma unroll
            for (int m = 0; m < 2; ++m) {
                int row = w * 32 + m * 16 + c;
                int chp = (kc * 4 + g) ^ (row & 7);
                a[m] = *(const bf16x8*)&sA[row * 64 + chp * 8];
            }
            #pragma unroll
            for (int n = 0; n < 8; ++n) {
                int row = n * 16 + c;
                int chp = (kc * 4 + g) ^ (row & 7);
                b[n] = *(const bf16x8*)&sB[row * 64 + chp * 8];
            }
            #pragma unroll
            for (int m = 0; m < 2; ++m)
                #pragma unroll
                for (int n = 0; n < 8; ++n)
                    acc[m][n] = __builtin_amdgcn_mfma_f32_16x16x32_bf16(a[m], b[n], acc[m][n], 0, 0, 0);
        }
    }

    if (bx < 32) {
        const bool isQ = (bx < 24);
        // attn scale * log2(e) folded into Q
        const float qscl = isQ ? (0.08838834764831845f * 1.4426950408889634f) : 1.0f;
        ushort* dst = isQ ? (Qb + (size_t)bx * T_SEQ * HD)
                          : (Kb + (size_t)(bx - 24) * T_SEQ * HD);
        #pragma unroll
        for (int m = 0; m < 2; ++m) {
            #pragma unroll
            for (int n = 0; n < 4; ++n) {
                #pragma unroll
                for (int r = 0; r < 4; ++r) {
                    int t = m0 + w * 32 + m * 16 + g * 4 + r;
                    int d = n * 16 + c;
                    float q1 = acc[m][n][r] * qscl, q2 = acc[m][n + 4][r] * qscl;
                    float cv = cosT[t * 64 + d], sv = sinT[t * 64 + d];
                    dst[(size_t)t * HD + d]      = f2bf(q1 * cv - q2 * sv);
                    dst[(size_t)t * HD + 64 + d] = f2bf(q2 * cv + q1 * sv);
                }
            }
        }
    } else {
        ushort* dst = Vt + (size_t)(bx - 32) * HD * T_SEQ;
        #pragma unroll
        for (int m = 0; m < 2; ++m) {
            #pragma unroll
            for (int n = 0; n < 8; ++n) {
                int d  = n * 16 + c;
                int t0 = m0 + w * 32 + m * 16 + g * 4;
                ushort4 pk;
                pk.x = f2bf(acc[m][n][0]); pk.y = f2bf(acc[m][n][1]);
                pk.z = f2bf(acc[m][n][2]); pk.w = f2bf(acc[m][n][3]);
                *(ushort4*)&dst[(size_t)d * T_SEQ + t0] = pk;
            }
        }
    }
}

// ---------------------------------------------------------------------------
// Flash attention v3: swapped QK^T (S = mfma(K,Q)) -> lane-local softmax
// (one q-row per lane, 16 keys in-register, 2 shuffles per reduce),
// exp2 domain (scale*log2e pre-folded into Q), defer-max (THR=8),
// LDS-staged double-buffered K/V via global_load_lds + XOR swizzle.
// ---------------------------------------------------------------------------
__global__ __launch_bounds__(256) void attn_mfma(
    const ushort* __restrict__ Qb, const ushort* __restrict__ Kb,
    const ushort* __restrict__ Vt, ushort* __restrict__ AO) {

    __shared__ ushort sK[2][64 * 128];
    __shared__ ushort sV[2][128 * 64];
    __shared__ ushort sP[4][16][72];

    const int qt = (int)(gridDim.x - 1 - blockIdx.x);   // long blocks first
    const int h  = blockIdx.y;
    const int kh = h / 3;
    const int tid = threadIdx.x;
    const int w = tid >> 6, l = tid & 63, g = l >> 4, c = l & 15;

    const ushort* Qp = Qb + (size_t)h  * T_SEQ * HD;
    const ushort* Kp = Kb + (size_t)kh * T_SEQ * HD;
    const ushort* Vp = Vt + (size_t)kh * HD * T_SEQ;

    const int myq = qt * 64 + w * 16 + c;   // this lane's q-row (B-col)
    bf16x8 qf[4];
    #pragma unroll
    for (int kc = 0; kc < 4; ++kc)
        qf[kc] = *(const bf16x8*)&Qp[(size_t)myq * HD + kc * 32 + g * 8];

    f32x4 o[8];
    #pragma unroll
    for (int n = 0; n < 8; ++n) o[n] = {0.f, 0.f, 0.f, 0.f};
    float m_run = -3.0e38f, l_run = 0.f;

    #define STAGE_KV(ktile, buf)                                                     \
        {                                                                            \
            _Pragma("unroll")                                                        \
            for (int u = 0; u < 4; ++u) {                                            \
                int chunk = (w * 4 + u) * 64 + l;                                    \
                int row = chunk >> 4;                                                \
                int sub = (chunk & 15) ^ (row & 7);                                  \
                gll16(Kp + (size_t)((ktile) * 64 + row) * HD + sub * 8,              \
                      &sK[buf][(w * 4 + u) * 512]);                                  \
            }                                                                        \
            _Pragma("unroll")                                                        \
            for (int u = 0; u < 4; ++u) {                                            \
                int chunk = (w * 4 + u) * 64 + l;                                    \
                int row = chunk >> 3;                                                \
                int sub = (chunk & 7) ^ (row & 7);                                   \
                gll16(Vp + (size_t)row * T_SEQ + (ktile) * 64 + sub * 8,             \
                      &sV[buf][(w * 4 + u) * 512]);                                  \
            }                                                                        \
        }

    int cur = 0;
    STAGE_KV(0, 0);
    __syncthreads();

    for (int kt = 0; kt <= qt; ++kt) {
        if (kt < qt) STAGE_KV(kt + 1, cur ^ 1);

        // ---- S^T = K Q^T : D[col=c -> q, row=g*4+r -> key] ----
        f32x4 sacc[4];
        #pragma unroll
        for (int nt = 0; nt < 4; ++nt) sacc[nt] = {0.f, 0.f, 0.f, 0.f};
        const ushort* sKc = &sK[cur][0];
        __builtin_amdgcn_s_setprio(1);
        #pragma unroll
        for (int nt = 0; nt < 4; ++nt) {
            int row = nt * 16 + c;
            #pragma unroll
            for (int kc = 0; kc < 4; ++kc) {
                int chp = (kc * 4 + g) ^ (row & 7);
                bf16x8 kf = *(const bf16x8*)&sKc[row * 128 + chp * 8];
                sacc[nt] = __builtin_amdgcn_mfma_f32_16x16x32_bf16(kf, qf[kc], sacc[nt], 0, 0, 0);
            }
        }
        __builtin_amdgcn_s_setprio(0);

        // ---- causal mask + lane-local online softmax (exp2 domain) ----
        float p[16];
        float pm = -3.0e38f;
        #pragma unroll
        for (int nt = 0; nt < 4; ++nt) {
            #pragma unroll
            for (int r = 0; r < 4; ++r) {
                int key = kt * 64 + nt * 16 + g * 4 + r;
                float s = sacc[nt][r];
                s = (key > myq) ? -3.0e38f : s;
                p[nt * 4 + r] = s;
                pm = fmaxf(pm, s);
            }
        }
        pm = fmaxf(pm, __shfl_xor(pm, 16));
        pm = fmaxf(pm, __shfl_xor(pm, 32));

        if (!__all(pm <= m_run + 8.0f)) {
            float mnew = fmaxf(m_run, pm);
            float alpha = fast_exp2(m_run - mnew);
            m_run = mnew;
            l_run *= alpha;
            float aR[4];
            #pragma unroll
            for (int r = 0; r < 4; ++r) aR[r] = __shfl(alpha, g * 4 + r);
            #pragma unroll
            for (int n = 0; n < 8; ++n) {
                f32x4 t = o[n];
                t[0] *= aR[0]; t[1] *= aR[1]; t[2] *= aR[2]; t[3] *= aR[3];
                o[n] = t;
            }
        }
        float psum = 0.f;
        #pragma unroll
        for (int i = 0; i < 16; ++i) {
            float e = fast_exp2(p[i] - m_run);
            p[i] = e;
            psum += e;
        }
        psum += __shfl_xor(psum, 16);
        psum += __shfl_xor(psum, 32);
        l_run += psum;

        // ---- pack P -> sP (row = q-row c, cols key) ----
        #pragma unroll
        for (int nt = 0; nt < 4; ++nt) {
            uint2 v;
            v.x = cvtpk_bf16(p[nt * 4 + 0], p[nt * 4 + 1]);
            v.y = cvtpk_bf16(p[nt * 4 + 2], p[nt * 4 + 3]);
            *(uint2*)&sP[w][c][nt * 16 + g * 4] = v;
        }

        // ---- PV: A = P (row=q), B = V^T (col=d) ----
        const ushort* sVc = &sV[cur][0];
        __builtin_amdgcn_s_setprio(1);
        #pragma unroll
        for (int kc2 = 0; kc2 < 2; ++kc2) {
            bf16x8 pa = *(const bf16x8*)&sP[w][c][kc2 * 32 + g * 8];
            #pragma unroll
            for (int n = 0; n < 8; ++n) {
                int row = n * 16 + c;
                int chp = (kc2 * 4 + g) ^ (row & 7);
                bf16x8 vf = *(const bf16x8*)&sVc[row * 64 + chp * 8];
                o[n] = __builtin_amdgcn_mfma_f32_16x16x32_bf16(pa, vf, o[n], 0, 0, 0);
            }
        }
        __builtin_amdgcn_s_setprio(0);

        __syncthreads();
        cur ^= 1;
    }
    #undef STAGE_KV

    // epilogue: o rows = q = qt*64 + w*16 + g*4 + r; l_run lives at lane c=q
    float invR[4];
    #pragma unroll
    for (int r = 0; r < 4; ++r) invR[r] = 1.0f / __shfl(l_run, g * 4 + r);
    #pragma unroll
    for (int n = 0; n < 8; ++n)
        #pragma unroll
        for (int r = 0; r < 4; ++r) {
            int t = qt * 64 + w * 16 + g * 4 + r;
            AO[(size_t)t * C_DIM + h * HD + n * 16 + c] = f2bf(o[n][r] * invR[r]);
        }
}

// ---------------------------------------------------------------------------
// Output projection: AO[2048,3072] bf16 @ WoT (n-major) -> fp32 out
// ---------------------------------------------------------------------------
__global__ __launch_bounds__(256) void out_gemm_mfma(
    const ushort* __restrict__ Ab, const ushort* __restrict__ BT,
    float* __restrict__ outp) {

    __shared__ ushort sA[128 * 64];
    __shared__ ushort sB[128 * 64];

    const int bx = blockIdx.x;
    const int by = blockIdx.y;
    const int tid = threadIdx.x;
    const int w = tid >> 6, l = tid & 63, g = l >> 4, c = l & 15;
    const int m0 = by * 128, n0 = bx * 128;

    f32x4 acc[2][8];
    #pragma unroll
    for (int m = 0; m < 2; ++m)
        #pragma unroll
        for (int n = 0; n < 8; ++n) acc[m][n] = {0.f, 0.f, 0.f, 0.f};

    const int ch = (w * 4) * 64 + l;
    for (int k0 = 0; k0 < C_DIM; k0 += 64) {
        __syncthreads();
        #pragma unroll
        for (int u = 0; u < 4; ++u) {
            int chu = ch + u * 64;
            int row = chu >> 3, sub = chu & 7;
            int sc  = sub ^ (row & 7);
            gll16(Ab + (size_t)(m0 + row) * C_DIM + k0 + sc * 8, &sA[(w * 4 + u) * 512]);
            gll16(BT + (size_t)(n0 + row) * C_DIM + k0 + sc * 8, &sB[(w * 4 + u) * 512]);
        }
        __syncthreads();

        #pragma unroll
        for (int kc = 0; kc < 2; ++kc) {
            bf16x8 a[2], b[8];
            #pragma unroll
            for (int m = 0; m < 2; ++m) {
                int row = w * 32 + m * 16 + c;
                int chp = (kc * 4 + g) ^ (row & 7);
                a[m] = *(const bf16x8*)&sA[row * 64 + chp * 8];
            }
            #pragma unroll
            for (int n = 0; n < 8; ++n) {
                int row = n * 16 + c;
                int chp = (kc * 4 + g) ^ (row & 7);
                b[n] = *(const bf16x8*)&sB[row * 64 + chp * 8];
            }
            #pragma unroll
            for (int m = 0; m < 2; ++m)
                #pragma unroll
                for (int n = 0; n < 8; ++n)
                    acc[m][n] = __builtin_amdgcn_mfma_f32_16x16x32_bf16(a[m], b[n], acc[m][n], 0, 0, 0);
        }
    }

    #pragma unroll
    for (int m = 0; m < 2; ++m)
        #pragma unroll
        for (int n = 0; n < 8; ++n)
            #pragma unroll
            for (int r = 0; r < 4; ++r) {
                int t = m0 + w * 32 + m * 16 + g * 4 + r;
                outp[(size_t)t * C_DIM + n0 + n * 16 + c] = acc[m][n][r];
            }
}

// ---------------------------------------------------------------------------
extern "C" void kernel_launch(void* const* d_in, const int* in_sizes, int n_in,
                              void* d_out, int out_size, void* d_ws, size_t ws_size,
                              hipStream_t stream) {
    const float* x  = (const float*)d_in[0];
    const float* Wq = (const float*)d_in[1];
    const float* Wk = (const float*)d_in[2];
    const float* Wv = (const float*)d_in[3];
    const float* Wo = (const float*)d_in[4];

    char* ws = (char*)d_ws;
    float*  cosT = (float*)ws;                         ws += 2048 * 64 * 4;
    float*  sinT = (float*)ws;                         ws += 2048 * 64 * 4;
    ushort* WbT  = (ushort*)ws;                        ws += (size_t)5120 * 3072 * 2;
    ushort* WoT  = (ushort*)ws;                        ws += (size_t)3072 * 3072 * 2;
    ushort* Qb   = (ushort*)ws;                        ws += (size_t)NH  * T_SEQ * HD * 2;
    ushort* Kb   = (ushort*)ws;                        ws += (size_t)NKV * T_SEQ * HD * 2;
    ushort* Vt   = (ushort*)ws;                        ws += (size_t)NKV * T_SEQ * HD * 2;
    ushort* xb   = (ushort*)ws;                        // 2048*3072*2
    ushort* AO   = xb;                                 // alias: xb dead after qkv_gemm
    float*  out  = (float*)d_out;

    rope_table <<<dim3(2048),   dim3(64),  0, stream>>>(cosT, sinT);
    convert_x  <<<dim3(2048),   dim3(256), 0, stream>>>(x, xb);
    transpose_w<<<dim3(48, 48), dim3(256), 0, stream>>>(Wq, WbT,                       3072);
    transpose_w<<<dim3(16, 48), dim3(256), 0, stream>>>(Wk, WbT + (size_t)3072 * 3072, 1024);
    transpose_w<<<dim3(16, 48), dim3(256), 0, stream>>>(Wv, WbT + (size_t)4096 * 3072, 1024);
    transpose_w<<<dim3(48, 48), dim3(256), 0, stream>>>(Wo, WoT,                       3072);

    qkv_gemm_mfma<<<dim3(40, 16), dim3(256), 0, stream>>>(xb, WbT, cosT, sinT, Qb, Kb, Vt);
    attn_mfma    <<<dim3(32, 24), dim3(256), 0, stream>>>(Qb, Kb, Vt, AO);
    out_gemm_mfma<<<dim3(24, 16), dim3(256), 0, stream>>>(AO, WoT, out);
}

// Round 5
// 407.179 us; speedup vs baseline: 6.1458x; 1.1133x over previous
//
#include <hip/hip_runtime.h>
#include <cstdint>

#define T_SEQ 2048
#define C_DIM 3072
#define NH    24
#define NKV   8
#define HD    128
#define N_TILES (32 * 24)

typedef short  bf16x8 __attribute__((ext_vector_type(8)));
typedef float  f32x4  __attribute__((ext_vector_type(4)));

__device__ __forceinline__ ushort f2bf(float f) {
    union { float f; uint32_t u; } v; v.f = f;
    uint32_t r = (v.u + 0x7FFF + ((v.u >> 16) & 1)) >> 16;
    return (ushort)r;
}

__device__ __forceinline__ uint32_t cvtpk_bf16(float lo, float hi) {
    uint32_t r;
    asm("v_cvt_pk_bf16_f32 %0, %1, %2" : "=v"(r) : "v"(lo), "v"(hi));
    return r;
}

__device__ __forceinline__ float fast_exp2(float x) {
#if __has_builtin(__builtin_amdgcn_exp2f)
    return __builtin_amdgcn_exp2f(x);
#else
    return exp2f(x);
#endif
}

__device__ __forceinline__ void gll16(const void* g, void* lds) {
    __builtin_amdgcn_global_load_lds(
        (const __attribute__((address_space(1))) uint32_t*)g,
        (__attribute__((address_space(3))) uint32_t*)lds, 16, 0, 0);
}

// ---------------------------------------------------------------------------
__global__ void zero_ctr(int* c) { *c = 0; }

// ---------------------------------------------------------------------------
// RoPE tables (fp32): cosT/sinT [2048][64]
// ---------------------------------------------------------------------------
__global__ __launch_bounds__(64) void rope_table(float* __restrict__ cosT,
                                                 float* __restrict__ sinT) {
    int t = blockIdx.x;
    int j = threadIdx.x;
    float inv = powf(10000.0f, -(float)j * (1.0f / 64.0f));
    float ang = (float)t * inv;
    cosT[t * 64 + j] = cosf(ang);
    sinT[t * 64 + j] = sinf(ang);
}

// ---------------------------------------------------------------------------
// x fp32 -> bf16
// ---------------------------------------------------------------------------
__global__ __launch_bounds__(256) void convert_x(const float* __restrict__ x,
                                                 ushort* __restrict__ xb) {
    int i = blockIdx.x * 256 + threadIdx.x;
    int stride = gridDim.x * 256;
    const int n4 = (T_SEQ * C_DIM) / 4;
    for (; i < n4; i += stride) {
        float4 v = ((const float4*)x)[i];
        ushort4 o;
        o.x = f2bf(v.x); o.y = f2bf(v.y); o.z = f2bf(v.z); o.w = f2bf(v.w);
        ((ushort4*)xb)[i] = o;
    }
}

// ---------------------------------------------------------------------------
// W [3072][ldN] fp32 -> dst [ldN][3072] bf16 (n-major transpose+convert)
// ---------------------------------------------------------------------------
__global__ __launch_bounds__(256) void transpose_w(const float* __restrict__ src,
                                                   ushort* __restrict__ dst,
                                                   int ldN) {
    __shared__ float sT[64][65];
    const int n0 = blockIdx.x * 64;
    const int k0 = blockIdx.y * 64;
    const int r  = threadIdx.x >> 4;
    const int c4 = (threadIdx.x & 15) * 4;
    #pragma unroll
    for (int i = 0; i < 4; ++i) {
        int kk = r + i * 16;
        float4 v = *(const float4*)&src[(size_t)(k0 + kk) * ldN + n0 + c4];
        sT[kk][c4 + 0] = v.x; sT[kk][c4 + 1] = v.y;
        sT[kk][c4 + 2] = v.z; sT[kk][c4 + 3] = v.w;
    }
    __syncthreads();
    #pragma unroll
    for (int i = 0; i < 4; ++i) {
        int nn = r + i * 16;
        ushort4 o;
        o.x = f2bf(sT[c4 + 0][nn]); o.y = f2bf(sT[c4 + 1][nn]);
        o.z = f2bf(sT[c4 + 2][nn]); o.w = f2bf(sT[c4 + 3][nn]);
        *(ushort4*)&dst[(size_t)(n0 + nn) * C_DIM + k0 + c4] = o;
    }
}

// ---------------------------------------------------------------------------
// QKV GEMM (bf16 MFMA) with fused RoPE epilogue. XCD-swizzled block id.
// Q heads scaled by 1/sqrt(128)*log2(e) (folded attn scale).
// ---------------------------------------------------------------------------
__global__ __launch_bounds__(256) void qkv_gemm_mfma(
    const ushort* __restrict__ xb, const ushort* __restrict__ WbT,
    const float* __restrict__ cosT, const float* __restrict__ sinT,
    ushort* __restrict__ Qb, ushort* __restrict__ Kb, ushort* __restrict__ Vt) {

    __shared__ ushort sA[128 * 64];
    __shared__ ushort sB[128 * 64];

    // 640 blocks = 8 XCDs x 80: contiguous logical range per XCD (2 A-row panels)
    const int bid = (int)blockIdx.x;
    const int swzb = (bid & 7) * 80 + (bid >> 3);
    const int bx = swzb % 40;       // 0..39 col tile (== one head)
    const int by = swzb / 40;       // 0..15 row tile
    const int tid = threadIdx.x;
    const int w = tid >> 6, l = tid & 63, g = l >> 4, c = l & 15;
    const int m0 = by * 128, n0 = bx * 128;

    f32x4 acc[2][8];
    #pragma unroll
    for (int m = 0; m < 2; ++m)
        #pragma unroll
        for (int n = 0; n < 8; ++n) acc[m][n] = {0.f, 0.f, 0.f, 0.f};

    const int ch = (w * 4) * 64 + l;
    for (int k0 = 0; k0 < C_DIM; k0 += 64) {
        __syncthreads();
        #pragma unroll
        for (int u = 0; u < 4; ++u) {
            int chu = ch + u * 64;
            int row = chu >> 3, sub = chu & 7;
            int sc  = sub ^ (row & 7);
            gll16(xb  + (size_t)(m0 + row) * C_DIM + k0 + sc * 8, &sA[(w * 4 + u) * 512]);
            gll16(WbT + (size_t)(n0 + row) * C_DIM + k0 + sc * 8, &sB[(w * 4 + u) * 512]);
        }
        __syncthreads();

        #pragma unroll
        for (int kc = 0; kc < 2; ++kc) {
            bf16x8 a[2], b[8];
            #pragma unroll
            for (int m = 0; m < 2; ++m) {
                int row = w * 32 + m * 16 + c;
                int chp = (kc * 4 + g) ^ (row & 7);
                a[m] = *(const bf16x8*)&sA[row * 64 + chp * 8];
            }
            #pragma unroll
            for (int n = 0; n < 8; ++n) {
                int row = n * 16 + c;
                int chp = (kc * 4 + g) ^ (row & 7);
                b[n] = *(const bf16x8*)&sB[row * 64 + chp * 8];
            }
            #pragma unroll
            for (int m = 0; m < 2; ++m)
                #pragma unroll
                for (int n = 0; n < 8; ++n)
                    acc[m][n] = __builtin_amdgcn_mfma_f32_16x16x32_bf16(a[m], b[n], acc[m][n], 0, 0, 0);
        }
    }

    if (bx < 32) {
        const bool isQ = (bx < 24);
        const float qscl = isQ ? (0.08838834764831845f * 1.4426950408889634f) : 1.0f;
        ushort* dst = isQ ? (Qb + (size_t)bx * T_SEQ * HD)
                          : (Kb + (size_t)(bx - 24) * T_SEQ * HD);
        #pragma unroll
        for (int m = 0; m < 2; ++m) {
            #pragma unroll
            for (int n = 0; n < 4; ++n) {
                #pragma unroll
                for (int r = 0; r < 4; ++r) {
                    int t = m0 + w * 32 + m * 16 + g * 4 + r;
                    int d = n * 16 + c;
                    float q1 = acc[m][n][r] * qscl, q2 = acc[m][n + 4][r] * qscl;
                    float cv = cosT[t * 64 + d], sv = sinT[t * 64 + d];
                    dst[(size_t)t * HD + d]      = f2bf(q1 * cv - q2 * sv);
                    dst[(size_t)t * HD + 64 + d] = f2bf(q2 * cv + q1 * sv);
                }
            }
        }
    } else {
        ushort* dst = Vt + (size_t)(bx - 32) * HD * T_SEQ;
        #pragma unroll
        for (int m = 0; m < 2; ++m) {
            #pragma unroll
            for (int n = 0; n < 8; ++n) {
                int d  = n * 16 + c;
                int t0 = m0 + w * 32 + m * 16 + g * 4;
                ushort4 pk;
                pk.x = f2bf(acc[m][n][0]); pk.y = f2bf(acc[m][n][1]);
                pk.z = f2bf(acc[m][n][2]); pk.w = f2bf(acc[m][n][3]);
                *(ushort4*)&dst[(size_t)d * T_SEQ + t0] = pk;
            }
        }
    }
}

// ---------------------------------------------------------------------------
// Flash attention v4: persistent blocks + dynamic LPT queue.
// 512 blocks (2/CU, all co-resident); tiles tau in [0,768), sorted by
// descending work: qt = 31 - tau/24, h = tau%24. Inner loop = round-4 v3
// (swapped QK^T, lane-local softmax in exp2 domain, defer-max, dbuf LDS K/V).
// ---------------------------------------------------------------------------
__global__ __launch_bounds__(256) void attn_mfma(
    const ushort* __restrict__ Qb, const ushort* __restrict__ Kb,
    const ushort* __restrict__ Vt, ushort* __restrict__ AO,
    int* __restrict__ ctr) {

    __shared__ ushort sK[2][64 * 128];
    __shared__ ushort sV[2][128 * 64];
    __shared__ ushort sP[4][16][72];
    __shared__ int s_tile;

    const int tid = threadIdx.x;
    const int w = tid >> 6, l = tid & 63, g = l >> 4, c = l & 15;

    for (;;) {
        if (tid == 0) s_tile = atomicAdd(ctr, 1);
        __syncthreads();
        const int tau = s_tile;
        if (tau >= N_TILES) break;
        const int qt = 31 - tau / 24;
        const int h  = tau % 24;
        const int kh = h / 3;

        const ushort* Qp = Qb + (size_t)h  * T_SEQ * HD;
        const ushort* Kp = Kb + (size_t)kh * T_SEQ * HD;
        const ushort* Vp = Vt + (size_t)kh * HD * T_SEQ;

        const int myq = qt * 64 + w * 16 + c;   // this lane's q-row (B-col)
        bf16x8 qf[4];
        #pragma unroll
        for (int kc = 0; kc < 4; ++kc)
            qf[kc] = *(const bf16x8*)&Qp[(size_t)myq * HD + kc * 32 + g * 8];

        f32x4 o[8];
        #pragma unroll
        for (int n = 0; n < 8; ++n) o[n] = {0.f, 0.f, 0.f, 0.f};
        float m_run = -3.0e38f, l_run = 0.f;

        #define STAGE_KV(ktile, buf)                                                 \
            {                                                                        \
                _Pragma("unroll")                                                    \
                for (int u = 0; u < 4; ++u) {                                        \
                    int chunk = (w * 4 + u) * 64 + l;                                \
                    int row = chunk >> 4;                                            \
                    int sub = (chunk & 15) ^ (row & 7);                              \
                    gll16(Kp + (size_t)((ktile) * 64 + row) * HD + sub * 8,          \
                          &sK[buf][(w * 4 + u) * 512]);                              \
                }                                                                    \
                _Pragma("unroll")                                                    \
                for (int u = 0; u < 4; ++u) {                                        \
                    int chunk = (w * 4 + u) * 64 + l;                                \
                    int row = chunk >> 3;                                            \
                    int sub = (chunk & 7) ^ (row & 7);                               \
                    gll16(Vp + (size_t)row * T_SEQ + (ktile) * 64 + sub * 8,         \
                          &sV[buf][(w * 4 + u) * 512]);                              \
                }                                                                    \
            }

        int cur = 0;
        STAGE_KV(0, 0);
        __syncthreads();   // also guards s_tile rewrite (first barrier after pop)

        for (int kt = 0; kt <= qt; ++kt) {
            if (kt < qt) STAGE_KV(kt + 1, cur ^ 1);

            // ---- S^T = K Q^T : D[col=c -> q, row=g*4+r -> key] ----
            f32x4 sacc[4];
            #pragma unroll
            for (int nt = 0; nt < 4; ++nt) sacc[nt] = {0.f, 0.f, 0.f, 0.f};
            const ushort* sKc = &sK[cur][0];
            __builtin_amdgcn_s_setprio(1);
            #pragma unroll
            for (int nt = 0; nt < 4; ++nt) {
                int row = nt * 16 + c;
                #pragma unroll
                for (int kc = 0; kc < 4; ++kc) {
                    int chp = (kc * 4 + g) ^ (row & 7);
                    bf16x8 kf = *(const bf16x8*)&sKc[row * 128 + chp * 8];
                    sacc[nt] = __builtin_amdgcn_mfma_f32_16x16x32_bf16(kf, qf[kc], sacc[nt], 0, 0, 0);
                }
            }
            __builtin_amdgcn_s_setprio(0);

            // ---- causal mask + lane-local online softmax (exp2 domain) ----
            float p[16];
            float pm = -3.0e38f;
            #pragma unroll
            for (int nt = 0; nt < 4; ++nt) {
                #pragma unroll
                for (int r = 0; r < 4; ++r) {
                    int key = kt * 64 + nt * 16 + g * 4 + r;
                    float s = sacc[nt][r];
                    s = (key > myq) ? -3.0e38f : s;
                    p[nt * 4 + r] = s;
                    pm = fmaxf(pm, s);
                }
            }
            pm = fmaxf(pm, __shfl_xor(pm, 16));
            pm = fmaxf(pm, __shfl_xor(pm, 32));

            if (!__all(pm <= m_run + 8.0f)) {
                float mnew = fmaxf(m_run, pm);
                float alpha = fast_exp2(m_run - mnew);
                m_run = mnew;
                l_run *= alpha;
                float aR[4];
                #pragma unroll
                for (int r = 0; r < 4; ++r) aR[r] = __shfl(alpha, g * 4 + r);
                #pragma unroll
                for (int n = 0; n < 8; ++n) {
                    f32x4 t = o[n];
                    t[0] *= aR[0]; t[1] *= aR[1]; t[2] *= aR[2]; t[3] *= aR[3];
                    o[n] = t;
                }
            }
            float psum = 0.f;
            #pragma unroll
            for (int i = 0; i < 16; ++i) {
                float e = fast_exp2(p[i] - m_run);
                p[i] = e;
                psum += e;
            }
            psum += __shfl_xor(psum, 16);
            psum += __shfl_xor(psum, 32);
            l_run += psum;

            // ---- pack P -> sP (row = q-row c, cols key) ----
            #pragma unroll
            for (int nt = 0; nt < 4; ++nt) {
                uint2 v;
                v.x = cvtpk_bf16(p[nt * 4 + 0], p[nt * 4 + 1]);
                v.y = cvtpk_bf16(p[nt * 4 + 2], p[nt * 4 + 3]);
                *(uint2*)&sP[w][c][nt * 16 + g * 4] = v;
            }

            // ---- PV: A = P (row=q), B = V^T (col=d) ----
            const ushort* sVc = &sV[cur][0];
            __builtin_amdgcn_s_setprio(1);
            #pragma unroll
            for (int kc2 = 0; kc2 < 2; ++kc2) {
                bf16x8 pa = *(const bf16x8*)&sP[w][c][kc2 * 32 + g * 8];
                #pragma unroll
                for (int n = 0; n < 8; ++n) {
                    int row = n * 16 + c;
                    int chp = (kc2 * 4 + g) ^ (row & 7);
                    bf16x8 vf = *(const bf16x8*)&sVc[row * 64 + chp * 8];
                    o[n] = __builtin_amdgcn_mfma_f32_16x16x32_bf16(pa, vf, o[n], 0, 0, 0);
                }
            }
            __builtin_amdgcn_s_setprio(0);

            __syncthreads();
            cur ^= 1;
        }
        #undef STAGE_KV

        // epilogue: rows q = qt*64 + w*16 + g*4 + r; l_run lives at lane c=q
        float invR[4];
        #pragma unroll
        for (int r = 0; r < 4; ++r) invR[r] = 1.0f / __shfl(l_run, g * 4 + r);
        #pragma unroll
        for (int n = 0; n < 8; ++n)
            #pragma unroll
            for (int r = 0; r < 4; ++r) {
                int t = qt * 64 + w * 16 + g * 4 + r;
                AO[(size_t)t * C_DIM + h * HD + n * 16 + c] = f2bf(o[n][r] * invR[r]);
            }
    }
}

// ---------------------------------------------------------------------------
// Output projection: AO[2048,3072] bf16 @ WoT (n-major) -> fp32 out
// XCD-swizzled block id (384 = 8 x 48).
// ---------------------------------------------------------------------------
__global__ __launch_bounds__(256) void out_gemm_mfma(
    const ushort* __restrict__ Ab, const ushort* __restrict__ BT,
    float* __restrict__ outp) {

    __shared__ ushort sA[128 * 64];
    __shared__ ushort sB[128 * 64];

    const int bid = (int)blockIdx.x;
    const int swzb = (bid & 7) * 48 + (bid >> 3);
    const int bx = swzb % 24;
    const int by = swzb / 24;
    const int tid = threadIdx.x;
    const int w = tid >> 6, l = tid & 63, g = l >> 4, c = l & 15;
    const int m0 = by * 128, n0 = bx * 128;

    f32x4 acc[2][8];
    #pragma unroll
    for (int m = 0; m < 2; ++m)
        #pragma unroll
        for (int n = 0; n < 8; ++n) acc[m][n] = {0.f, 0.f, 0.f, 0.f};

    const int ch = (w * 4) * 64 + l;
    for (int k0 = 0; k0 < C_DIM; k0 += 64) {
        __syncthreads();
        #pragma unroll
        for (int u = 0; u < 4; ++u) {
            int chu = ch + u * 64;
            int row = chu >> 3, sub = chu & 7;
            int sc  = sub ^ (row & 7);
            gll16(Ab + (size_t)(m0 + row) * C_DIM + k0 + sc * 8, &sA[(w * 4 + u) * 512]);
            gll16(BT + (size_t)(n0 + row) * C_DIM + k0 + sc * 8, &sB[(w * 4 + u) * 512]);
        }
        __syncthreads();

        #pragma unroll
        for (int kc = 0; kc < 2; ++kc) {
            bf16x8 a[2], b[8];
            #pragma unroll
            for (int m = 0; m < 2; ++m) {
                int row = w * 32 + m * 16 + c;
                int chp = (kc * 4 + g) ^ (row & 7);
                a[m] = *(const bf16x8*)&sA[row * 64 + chp * 8];
            }
            #pragma unroll
            for (int n = 0; n < 8; ++n) {
                int row = n * 16 + c;
                int chp = (kc * 4 + g) ^ (row & 7);
                b[n] = *(const bf16x8*)&sB[row * 64 + chp * 8];
            }
            #pragma unroll
            for (int m = 0; m < 2; ++m)
                #pragma unroll
                for (int n = 0; n < 8; ++n)
                    acc[m][n] = __builtin_amdgcn_mfma_f32_16x16x32_bf16(a[m], b[n], acc[m][n], 0, 0, 0);
        }
    }

    #pragma unroll
    for (int m = 0; m < 2; ++m)
        #pragma unroll
        for (int n = 0; n < 8; ++n)
            #pragma unroll
            for (int r = 0; r < 4; ++r) {
                int t = m0 + w * 32 + m * 16 + g * 4 + r;
                outp[(size_t)t * C_DIM + n0 + n * 16 + c] = acc[m][n][r];
            }
}

// ---------------------------------------------------------------------------
extern "C" void kernel_launch(void* const* d_in, const int* in_sizes, int n_in,
                              void* d_out, int out_size, void* d_ws, size_t ws_size,
                              hipStream_t stream) {
    const float* x  = (const float*)d_in[0];
    const float* Wq = (const float*)d_in[1];
    const float* Wk = (const float*)d_in[2];
    const float* Wv = (const float*)d_in[3];
    const float* Wo = (const float*)d_in[4];

    char* ws = (char*)d_ws;
    int*    ctr  = (int*)ws;                           ws += 256;
    float*  cosT = (float*)ws;                         ws += 2048 * 64 * 4;
    float*  sinT = (float*)ws;                         ws += 2048 * 64 * 4;
    ushort* WbT  = (ushort*)ws;                        ws += (size_t)5120 * 3072 * 2;
    ushort* WoT  = (ushort*)ws;                        ws += (size_t)3072 * 3072 * 2;
    ushort* Qb   = (ushort*)ws;                        ws += (size_t)NH  * T_SEQ * HD * 2;
    ushort* Kb   = (ushort*)ws;                        ws += (size_t)NKV * T_SEQ * HD * 2;
    ushort* Vt   = (ushort*)ws;                        ws += (size_t)NKV * T_SEQ * HD * 2;
    ushort* xb   = (ushort*)ws;                        // 2048*3072*2
    ushort* AO   = xb;                                 // alias: xb dead after qkv_gemm
    float*  out  = (float*)d_out;

    zero_ctr   <<<dim3(1),      dim3(1),   0, stream>>>(ctr);
    rope_table <<<dim3(2048),   dim3(64),  0, stream>>>(cosT, sinT);
    convert_x  <<<dim3(2048),   dim3(256), 0, stream>>>(x, xb);
    transpose_w<<<dim3(48, 48), dim3(256), 0, stream>>>(Wq, WbT,                       3072);
    transpose_w<<<dim3(16, 48), dim3(256), 0, stream>>>(Wk, WbT + (size_t)3072 * 3072, 1024);
    transpose_w<<<dim3(16, 48), dim3(256), 0, stream>>>(Wv, WbT + (size_t)4096 * 3072, 1024);
    transpose_w<<<dim3(48, 48), dim3(256), 0, stream>>>(Wo, WoT,                       3072);

    qkv_gemm_mfma<<<dim3(640), dim3(256), 0, stream>>>(xb, WbT, cosT, sinT, Qb, Kb, Vt);
    attn_mfma    <<<dim3(512), dim3(256), 0, stream>>>(Qb, Kb, Vt, AO, ctr);
    out_gemm_mfma<<<dim3(384), dim3(256), 0, stream>>>(AO, WoT, out);
}

// Round 6
// 385.412 us; speedup vs baseline: 6.4929x; 1.0565x over previous
//
#include <hip/hip_runtime.h>
#include <cstdint>

#define T_SEQ 2048
#define C_DIM 3072
#define NH    24
#define NKV   8
#define HD    128
#define N_TILES (32 * 24)

typedef short  bf16x8 __attribute__((ext_vector_type(8)));
typedef float  f32x4  __attribute__((ext_vector_type(4)));

__device__ __forceinline__ ushort f2bf(float f) {
    union { float f; uint32_t u; } v; v.f = f;
    uint32_t r = (v.u + 0x7FFF + ((v.u >> 16) & 1)) >> 16;
    return (ushort)r;
}

__device__ __forceinline__ uint32_t cvtpk_bf16(float lo, float hi) {
    uint32_t r;
    asm("v_cvt_pk_bf16_f32 %0, %1, %2" : "=v"(r) : "v"(lo), "v"(hi));
    return r;
}

__device__ __forceinline__ float fast_exp2(float x) {
#if __has_builtin(__builtin_amdgcn_exp2f)
    return __builtin_amdgcn_exp2f(x);
#else
    return exp2f(x);
#endif
}

__device__ __forceinline__ void gll16(const void* g, void* lds) {
    __builtin_amdgcn_global_load_lds(
        (const __attribute__((address_space(1))) uint32_t*)g,
        (__attribute__((address_space(3))) uint32_t*)lds, 16, 0, 0);
}

// ---------------------------------------------------------------------------
// prep: RoPE tables + ctr zero + x fp32->bf16 (merged, one launch)
// grid 2048 x 256
// ---------------------------------------------------------------------------
__global__ __launch_bounds__(256) void prep(const float* __restrict__ x,
                                            ushort* __restrict__ xb,
                                            float* __restrict__ cosT,
                                            float* __restrict__ sinT,
                                            int* __restrict__ ctr) {
    const int t = blockIdx.x;
    const int tid = threadIdx.x;
    if (t == 0 && tid == 0) *ctr = 0;
    if (tid < 64) {
        float inv = powf(10000.0f, -(float)tid * (1.0f / 64.0f));
        float ang = (float)t * inv;
        cosT[t * 64 + tid] = cosf(ang);
        sinT[t * 64 + tid] = sinf(ang);
    }
    const int n4 = (T_SEQ * C_DIM) / 4;
    const int stride = gridDim.x * 256;
    for (int i = t * 256 + tid; i < n4; i += stride) {
        float4 v = ((const float4*)x)[i];
        ushort4 o;
        o.x = f2bf(v.x); o.y = f2bf(v.y); o.z = f2bf(v.z); o.w = f2bf(v.w);
        ((ushort4*)xb)[i] = o;
    }
}

// ---------------------------------------------------------------------------
// All four weight transposes in one launch.
// grid (128, 48): bx<48 Wq | <64 Wk | <80 Wv | <128 Wo. 64x64 tiles.
// src [3072][ldN] fp32 -> dst [ldN][3072] bf16 (n-major)
// ---------------------------------------------------------------------------
__global__ __launch_bounds__(256) void transpose_all(
    const float* __restrict__ Wq, const float* __restrict__ Wk,
    const float* __restrict__ Wv, const float* __restrict__ Wo,
    ushort* __restrict__ WbT, ushort* __restrict__ WoT) {

    __shared__ float sT[64][65];
    const int bx = blockIdx.x;
    const float* src; ushort* dst; int ldN, nstrip;
    if (bx < 48)      { src = Wq; dst = WbT;                       ldN = 3072; nstrip = bx; }
    else if (bx < 64) { src = Wk; dst = WbT + (size_t)3072 * 3072; ldN = 1024; nstrip = bx - 48; }
    else if (bx < 80) { src = Wv; dst = WbT + (size_t)4096 * 3072; ldN = 1024; nstrip = bx - 64; }
    else              { src = Wo; dst = WoT;                       ldN = 3072; nstrip = bx - 80; }

    const int n0 = nstrip * 64;
    const int k0 = blockIdx.y * 64;
    const int r  = threadIdx.x >> 4;
    const int c4 = (threadIdx.x & 15) * 4;
    #pragma unroll
    for (int i = 0; i < 4; ++i) {
        int kk = r + i * 16;
        float4 v = *(const float4*)&src[(size_t)(k0 + kk) * ldN + n0 + c4];
        sT[kk][c4 + 0] = v.x; sT[kk][c4 + 1] = v.y;
        sT[kk][c4 + 2] = v.z; sT[kk][c4 + 3] = v.w;
    }
    __syncthreads();
    #pragma unroll
    for (int i = 0; i < 4; ++i) {
        int nn = r + i * 16;
        ushort4 o;
        o.x = f2bf(sT[c4 + 0][nn]); o.y = f2bf(sT[c4 + 1][nn]);
        o.z = f2bf(sT[c4 + 2][nn]); o.w = f2bf(sT[c4 + 3][nn]);
        *(ushort4*)&dst[(size_t)(n0 + nn) * C_DIM + k0 + c4] = o;
    }
}

// ---------------------------------------------------------------------------
// QKV GEMM (bf16 MFMA), 64x128 tile (M-split for residency: 1280 blocks,
// ~5 blocks/CU). 4 waves; wave w owns rows w*16..+15, acc[8] frags.
// Fused RoPE epilogue (full head per N-tile). Q scaled by 1/sqrt(128)*log2e.
// ---------------------------------------------------------------------------
__global__ __launch_bounds__(256) void qkv_gemm_mfma(
    const ushort* __restrict__ xb, const ushort* __restrict__ WbT,
    const float* __restrict__ cosT, const float* __restrict__ sinT,
    ushort* __restrict__ Qb, ushort* __restrict__ Kb, ushort* __restrict__ Vt) {

    __shared__ ushort sA[64 * 64];     // 8 KB
    __shared__ ushort sB[128 * 64];    // 16 KB

    // 1280 = 8 XCDs x 160, bijective swizzle; ids ordered by A-row panel
    const int bid  = (int)blockIdx.x;
    const int swzb = (bid & 7) * 160 + (bid >> 3);
    const int by = swzb / 40;          // 0..31 (64-row M tile)
    const int bx = swzb % 40;          // 0..39 (head)
    const int tid = threadIdx.x;
    const int w = tid >> 6, l = tid & 63, g = l >> 4, c = l & 15;
    const int m0 = by * 64, n0 = bx * 128;

    f32x4 acc[8];
    #pragma unroll
    for (int n = 0; n < 8; ++n) acc[n] = {0.f, 0.f, 0.f, 0.f};

    for (int k0 = 0; k0 < C_DIM; k0 += 64) {
        __syncthreads();
        #pragma unroll
        for (int u = 0; u < 2; ++u) {              // A: 64x64, 2 chunks/thread
            int chu = (w * 2 + u) * 64 + l;
            int row = chu >> 3, sub = chu & 7;
            int sc  = sub ^ (row & 7);
            gll16(xb + (size_t)(m0 + row) * C_DIM + k0 + sc * 8, &sA[(w * 2 + u) * 512]);
        }
        #pragma unroll
        for (int u = 0; u < 4; ++u) {              // B: 128x64, 4 chunks/thread
            int chu = (w * 4 + u) * 64 + l;
            int row = chu >> 3, sub = chu & 7;
            int sc  = sub ^ (row & 7);
            gll16(WbT + (size_t)(n0 + row) * C_DIM + k0 + sc * 8, &sB[(w * 4 + u) * 512]);
        }
        __syncthreads();

        #pragma unroll
        for (int kc = 0; kc < 2; ++kc) {
            int arow = w * 16 + c;
            int achp = (kc * 4 + g) ^ (arow & 7);
            bf16x8 av = *(const bf16x8*)&sA[arow * 64 + achp * 8];
            #pragma unroll
            for (int n = 0; n < 8; ++n) {
                int brow = n * 16 + c;
                int chp  = (kc * 4 + g) ^ (brow & 7);
                bf16x8 bv = *(const bf16x8*)&sB[brow * 64 + chp * 8];
                acc[n] = __builtin_amdgcn_mfma_f32_16x16x32_bf16(av, bv, acc[n], 0, 0, 0);
            }
        }
    }

    if (bx < 32) {
        const bool isQ = (bx < 24);
        const float qscl = isQ ? (0.08838834764831845f * 1.4426950408889634f) : 1.0f;
        ushort* dst = isQ ? (Qb + (size_t)bx * T_SEQ * HD)
                          : (Kb + (size_t)(bx - 24) * T_SEQ * HD);
        #pragma unroll
        for (int n = 0; n < 4; ++n) {
            #pragma unroll
            for (int r = 0; r < 4; ++r) {
                int t = m0 + w * 16 + g * 4 + r;
                int d = n * 16 + c;
                float q1 = acc[n][r] * qscl, q2 = acc[n + 4][r] * qscl;
                float cv = cosT[t * 64 + d], sv = sinT[t * 64 + d];
                dst[(size_t)t * HD + d]      = f2bf(q1 * cv - q2 * sv);
                dst[(size_t)t * HD + 64 + d] = f2bf(q2 * cv + q1 * sv);
            }
        }
    } else {
        ushort* dst = Vt + (size_t)(bx - 32) * HD * T_SEQ;
        #pragma unroll
        for (int n = 0; n < 8; ++n) {
            int d  = n * 16 + c;
            int t0 = m0 + w * 16 + g * 4;
            ushort4 pk;
            pk.x = f2bf(acc[n][0]); pk.y = f2bf(acc[n][1]);
            pk.z = f2bf(acc[n][2]); pk.w = f2bf(acc[n][3]);
            *(ushort4*)&dst[(size_t)d * T_SEQ + t0] = pk;
        }
    }
}

// ---------------------------------------------------------------------------
// Flash attention v4 (unchanged from round 5): persistent blocks + LPT queue,
// swapped QK^T, lane-local softmax (exp2 domain), defer-max, dbuf LDS K/V.
// ---------------------------------------------------------------------------
__global__ __launch_bounds__(256) void attn_mfma(
    const ushort* __restrict__ Qb, const ushort* __restrict__ Kb,
    const ushort* __restrict__ Vt, ushort* __restrict__ AO,
    int* __restrict__ ctr) {

    __shared__ ushort sK[2][64 * 128];
    __shared__ ushort sV[2][128 * 64];
    __shared__ ushort sP[4][16][72];
    __shared__ int s_tile;

    const int tid = threadIdx.x;
    const int w = tid >> 6, l = tid & 63, g = l >> 4, c = l & 15;

    for (;;) {
        if (tid == 0) s_tile = atomicAdd(ctr, 1);
        __syncthreads();
        const int tau = s_tile;
        if (tau >= N_TILES) break;
        const int qt = 31 - tau / 24;
        const int h  = tau % 24;
        const int kh = h / 3;

        const ushort* Qp = Qb + (size_t)h  * T_SEQ * HD;
        const ushort* Kp = Kb + (size_t)kh * T_SEQ * HD;
        const ushort* Vp = Vt + (size_t)kh * HD * T_SEQ;

        const int myq = qt * 64 + w * 16 + c;
        bf16x8 qf[4];
        #pragma unroll
        for (int kc = 0; kc < 4; ++kc)
            qf[kc] = *(const bf16x8*)&Qp[(size_t)myq * HD + kc * 32 + g * 8];

        f32x4 o[8];
        #pragma unroll
        for (int n = 0; n < 8; ++n) o[n] = {0.f, 0.f, 0.f, 0.f};
        float m_run = -3.0e38f, l_run = 0.f;

        #define STAGE_KV(ktile, buf)                                                 \
            {                                                                        \
                _Pragma("unroll")                                                    \
                for (int u = 0; u < 4; ++u) {                                        \
                    int chunk = (w * 4 + u) * 64 + l;                                \
                    int row = chunk >> 4;                                            \
                    int sub = (chunk & 15) ^ (row & 7);                              \
                    gll16(Kp + (size_t)((ktile) * 64 + row) * HD + sub * 8,          \
                          &sK[buf][(w * 4 + u) * 512]);                              \
                }                                                                    \
                _Pragma("unroll")                                                    \
                for (int u = 0; u < 4; ++u) {                                        \
                    int chunk = (w * 4 + u) * 64 + l;                                \
                    int row = chunk >> 3;                                            \
                    int sub = (chunk & 7) ^ (row & 7);                               \
                    gll16(Vp + (size_t)row * T_SEQ + (ktile) * 64 + sub * 8,         \
                          &sV[buf][(w * 4 + u) * 512]);                              \
                }                                                                    \
            }

        int cur = 0;
        STAGE_KV(0, 0);
        __syncthreads();

        for (int kt = 0; kt <= qt; ++kt) {
            if (kt < qt) STAGE_KV(kt + 1, cur ^ 1);

            f32x4 sacc[4];
            #pragma unroll
            for (int nt = 0; nt < 4; ++nt) sacc[nt] = {0.f, 0.f, 0.f, 0.f};
            const ushort* sKc = &sK[cur][0];
            __builtin_amdgcn_s_setprio(1);
            #pragma unroll
            for (int nt = 0; nt < 4; ++nt) {
                int row = nt * 16 + c;
                #pragma unroll
                for (int kc = 0; kc < 4; ++kc) {
                    int chp = (kc * 4 + g) ^ (row & 7);
                    bf16x8 kf = *(const bf16x8*)&sKc[row * 128 + chp * 8];
                    sacc[nt] = __builtin_amdgcn_mfma_f32_16x16x32_bf16(kf, qf[kc], sacc[nt], 0, 0, 0);
                }
            }
            __builtin_amdgcn_s_setprio(0);

            float p[16];
            float pm = -3.0e38f;
            #pragma unroll
            for (int nt = 0; nt < 4; ++nt) {
                #pragma unroll
                for (int r = 0; r < 4; ++r) {
                    int key = kt * 64 + nt * 16 + g * 4 + r;
                    float s = sacc[nt][r];
                    s = (key > myq) ? -3.0e38f : s;
                    p[nt * 4 + r] = s;
                    pm = fmaxf(pm, s);
                }
            }
            pm = fmaxf(pm, __shfl_xor(pm, 16));
            pm = fmaxf(pm, __shfl_xor(pm, 32));

            if (!__all(pm <= m_run + 8.0f)) {
                float mnew = fmaxf(m_run, pm);
                float alpha = fast_exp2(m_run - mnew);
                m_run = mnew;
                l_run *= alpha;
                float aR[4];
                #pragma unroll
                for (int r = 0; r < 4; ++r) aR[r] = __shfl(alpha, g * 4 + r);
                #pragma unroll
                for (int n = 0; n < 8; ++n) {
                    f32x4 t = o[n];
                    t[0] *= aR[0]; t[1] *= aR[1]; t[2] *= aR[2]; t[3] *= aR[3];
                    o[n] = t;
                }
            }
            float psum = 0.f;
            #pragma unroll
            for (int i = 0; i < 16; ++i) {
                float e = fast_exp2(p[i] - m_run);
                p[i] = e;
                psum += e;
            }
            psum += __shfl_xor(psum, 16);
            psum += __shfl_xor(psum, 32);
            l_run += psum;

            #pragma unroll
            for (int nt = 0; nt < 4; ++nt) {
                uint2 v;
                v.x = cvtpk_bf16(p[nt * 4 + 0], p[nt * 4 + 1]);
                v.y = cvtpk_bf16(p[nt * 4 + 2], p[nt * 4 + 3]);
                *(uint2*)&sP[w][c][nt * 16 + g * 4] = v;
            }

            const ushort* sVc = &sV[cur][0];
            __builtin_amdgcn_s_setprio(1);
            #pragma unroll
            for (int kc2 = 0; kc2 < 2; ++kc2) {
                bf16x8 pa = *(const bf16x8*)&sP[w][c][kc2 * 32 + g * 8];
                #pragma unroll
                for (int n = 0; n < 8; ++n) {
                    int row = n * 16 + c;
                    int chp = (kc2 * 4 + g) ^ (row & 7);
                    bf16x8 vf = *(const bf16x8*)&sVc[row * 64 + chp * 8];
                    o[n] = __builtin_amdgcn_mfma_f32_16x16x32_bf16(pa, vf, o[n], 0, 0, 0);
                }
            }
            __builtin_amdgcn_s_setprio(0);

            __syncthreads();
            cur ^= 1;
        }
        #undef STAGE_KV

        float invR[4];
        #pragma unroll
        for (int r = 0; r < 4; ++r) invR[r] = 1.0f / __shfl(l_run, g * 4 + r);
        #pragma unroll
        for (int n = 0; n < 8; ++n)
            #pragma unroll
            for (int r = 0; r < 4; ++r) {
                int t = qt * 64 + w * 16 + g * 4 + r;
                AO[(size_t)t * C_DIM + h * HD + n * 16 + c] = f2bf(o[n][r] * invR[r]);
            }
    }
}

// ---------------------------------------------------------------------------
// Output projection, 64x128 tile (768 blocks, 3/CU): AO bf16 @ WoT -> fp32
// ---------------------------------------------------------------------------
__global__ __launch_bounds__(256) void out_gemm_mfma(
    const ushort* __restrict__ Ab, const ushort* __restrict__ BT,
    float* __restrict__ outp) {

    __shared__ ushort sA[64 * 64];
    __shared__ ushort sB[128 * 64];

    const int bid  = (int)blockIdx.x;
    const int swzb = (bid & 7) * 96 + (bid >> 3);   // 768 = 8 x 96, bijective
    const int by = swzb / 24;        // 0..31
    const int bx = swzb % 24;        // 0..23
    const int tid = threadIdx.x;
    const int w = tid >> 6, l = tid & 63, g = l >> 4, c = l & 15;
    const int m0 = by * 64, n0 = bx * 128;

    f32x4 acc[8];
    #pragma unroll
    for (int n = 0; n < 8; ++n) acc[n] = {0.f, 0.f, 0.f, 0.f};

    for (int k0 = 0; k0 < C_DIM; k0 += 64) {
        __syncthreads();
        #pragma unroll
        for (int u = 0; u < 2; ++u) {
            int chu = (w * 2 + u) * 64 + l;
            int row = chu >> 3, sub = chu & 7;
            int sc  = sub ^ (row & 7);
            gll16(Ab + (size_t)(m0 + row) * C_DIM + k0 + sc * 8, &sA[(w * 2 + u) * 512]);
        }
        #pragma unroll
        for (int u = 0; u < 4; ++u) {
            int chu = (w * 4 + u) * 64 + l;
            int row = chu >> 3, sub = chu & 7;
            int sc  = sub ^ (row & 7);
            gll16(BT + (size_t)(n0 + row) * C_DIM + k0 + sc * 8, &sB[(w * 4 + u) * 512]);
        }
        __syncthreads();

        #pragma unroll
        for (int kc = 0; kc < 2; ++kc) {
            int arow = w * 16 + c;
            int achp = (kc * 4 + g) ^ (arow & 7);
            bf16x8 av = *(const bf16x8*)&sA[arow * 64 + achp * 8];
            #pragma unroll
            for (int n = 0; n < 8; ++n) {
                int brow = n * 16 + c;
                int chp  = (kc * 4 + g) ^ (brow & 7);
                bf16x8 bv = *(const bf16x8*)&sB[brow * 64 + chp * 8];
                acc[n] = __builtin_amdgcn_mfma_f32_16x16x32_bf16(av, bv, acc[n], 0, 0, 0);
            }
        }
    }

    #pragma unroll
    for (int n = 0; n < 8; ++n)
        #pragma unroll
        for (int r = 0; r < 4; ++r) {
            int t = m0 + w * 16 + g * 4 + r;
            outp[(size_t)t * C_DIM + n0 + n * 16 + c] = acc[n][r];
        }
}

// ---------------------------------------------------------------------------
extern "C" void kernel_launch(void* const* d_in, const int* in_sizes, int n_in,
                              void* d_out, int out_size, void* d_ws, size_t ws_size,
                              hipStream_t stream) {
    const float* x  = (const float*)d_in[0];
    const float* Wq = (const float*)d_in[1];
    const float* Wk = (const float*)d_in[2];
    const float* Wv = (const float*)d_in[3];
    const float* Wo = (const float*)d_in[4];

    char* ws = (char*)d_ws;
    int*    ctr  = (int*)ws;                           ws += 256;
    float*  cosT = (float*)ws;                         ws += 2048 * 64 * 4;
    float*  sinT = (float*)ws;                         ws += 2048 * 64 * 4;
    ushort* WbT  = (ushort*)ws;                        ws += (size_t)5120 * 3072 * 2;
    ushort* WoT  = (ushort*)ws;                        ws += (size_t)3072 * 3072 * 2;
    ushort* Qb   = (ushort*)ws;                        ws += (size_t)NH  * T_SEQ * HD * 2;
    ushort* Kb   = (ushort*)ws;                        ws += (size_t)NKV * T_SEQ * HD * 2;
    ushort* Vt   = (ushort*)ws;                        ws += (size_t)NKV * T_SEQ * HD * 2;
    ushort* xb   = (ushort*)ws;                        // 2048*3072*2
    ushort* AO   = xb;                                 // alias: xb dead after qkv_gemm
    float*  out  = (float*)d_out;

    prep         <<<dim3(2048),    dim3(256), 0, stream>>>(x, xb, cosT, sinT, ctr);
    transpose_all<<<dim3(128, 48), dim3(256), 0, stream>>>(Wq, Wk, Wv, Wo, WbT, WoT);
    qkv_gemm_mfma<<<dim3(1280),    dim3(256), 0, stream>>>(xb, WbT, cosT, sinT, Qb, Kb, Vt);
    attn_mfma    <<<dim3(512),     dim3(256), 0, stream>>>(Qb, Kb, Vt, AO, ctr);
    out_gemm_mfma<<<dim3(768),     dim3(256), 0, stream>>>(AO, WoT, out);
}